// Round 7
// baseline (214.296 us; speedup 1.0000x reference)
//
#include <hip/hip_runtime.h>

constexpr int C = 768;
constexpr int NPATCH = 1024;   // (448/14)^2
constexpr int H = 448, W = 448;
constexpr int HW = H * W;      // 200704
constexpr int TOPK = 200;      // int(200704 * 0.001)
constexpr float EPS = 1e-12f;

constexpr int HBITS = 13;
constexpr int HBINS = 1 << HBITS;   // 8192
constexpr int HSHIFT = 18;          // bin = float_bits >> 18 (sign always 0)
constexpr int SLICES = 32;          // hist blocks per batch
constexpr int CSTRIDE = 64;         // ints between per-batch counters (256B)

typedef float f32x4 __attribute__((ext_vector_type(4)));

__device__ __forceinline__ float dotv(const f32x4 a, const f32x4 b) {
    return a.x * b.x + a.y * b.y + a.z * b.z + a.w * b.w;
}

// One wave per (b,n) row, nontemporal (nt) loads: stream past L2/L3.
// Tests whether the ~2.9 TB/s plateau is an L3-path artifact or a true
// device read ceiling.
__global__ __launch_bounds__(256, 4) void anom_kernel(
    const float* __restrict__ m, const float* __restrict__ l,
    const float* __restrict__ pm, const float* __restrict__ pl,
    float* __restrict__ combined, int rows) {
    int wid = (int)((blockIdx.x * blockDim.x + threadIdx.x) >> 6);
    int lane = threadIdx.x & 63;
    if (wid >= rows) return;
    size_t base = (size_t)wid * C;
    const f32x4* A = (const f32x4*)(m + base);
    const f32x4* B = (const f32x4*)(pm + base);
    const f32x4* Cc = (const f32x4*)(l + base);
    const f32x4* D = (const f32x4*)(pl + base);

    f32x4 a0 = __builtin_nontemporal_load(A + lane);
    f32x4 a1 = __builtin_nontemporal_load(A + lane + 64);
    f32x4 a2 = __builtin_nontemporal_load(A + lane + 128);
    f32x4 b0 = __builtin_nontemporal_load(B + lane);
    f32x4 b1 = __builtin_nontemporal_load(B + lane + 64);
    f32x4 b2 = __builtin_nontemporal_load(B + lane + 128);
    f32x4 c0 = __builtin_nontemporal_load(Cc + lane);
    f32x4 c1 = __builtin_nontemporal_load(Cc + lane + 64);
    f32x4 c2 = __builtin_nontemporal_load(Cc + lane + 128);
    f32x4 d0 = __builtin_nontemporal_load(D + lane);
    f32x4 d1 = __builtin_nontemporal_load(D + lane + 64);
    f32x4 d2 = __builtin_nontemporal_load(D + lane + 128);

    float mm = dotv(a0, a0) + dotv(a1, a1) + dotv(a2, a2);
    float pp = dotv(b0, b0) + dotv(b1, b1) + dotv(b2, b2);
    float mp = dotv(a0, b0) + dotv(a1, b1) + dotv(a2, b2);
    float ll = dotv(c0, c0) + dotv(c1, c1) + dotv(c2, c2);
    float qq = dotv(d0, d0) + dotv(d1, d1) + dotv(d2, d2);
    float lq = dotv(c0, d0) + dotv(c1, d1) + dotv(c2, d2);

#pragma unroll
    for (int off = 32; off > 0; off >>= 1) {
        mm += __shfl_xor(mm, off);
        pp += __shfl_xor(pp, off);
        mp += __shfl_xor(mp, off);
        ll += __shfl_xor(ll, off);
        qq += __shfl_xor(qq, off);
        lq += __shfl_xor(lq, off);
    }
    if (lane == 0) {
        float rm = 1.0f / fmaxf(sqrtf(mm), EPS);
        float rp = 1.0f / fmaxf(sqrtf(pp), EPS);
        float rl = 1.0f / fmaxf(sqrtf(ll), EPS);
        float rq = 1.0f / fmaxf(sqrtf(qq), EPS);
        float d2m = fmaxf(mm * rm * rm - 2.f * mp * rm * rp + pp * rp * rp, 0.f);
        float d2l = fmaxf(ll * rl * rl - 2.f * lq * rl * rq + qq * rq * rq, 0.f);
        combined[wid] = sqrtf(d2m) * sqrtf(d2l);
    }
}

__device__ __forceinline__ float bilerp32(const float* __restrict__ s,
                                          int gy, int gx) {
    float sx = (gx + 0.5f) * (1.0f / 14.0f) - 0.5f;
    float sy = (gy + 0.5f) * (1.0f / 14.0f) - 0.5f;
    float fx0 = floorf(sx), fy0 = floorf(sy);
    float fx = sx - fx0, fy = sy - fy0;
    int x0 = (int)fx0, y0 = (int)fy0;
    int x0c = min(max(x0, 0), 31);
    int x1c = min(max(x0 + 1, 0), 31);
    int y0c = min(max(y0, 0), 31);
    int y1c = min(max(y0 + 1, 0), 31);
    float v00 = s[y0c * 32 + x0c], v01 = s[y0c * 32 + x1c];
    float v10 = s[y1c * 32 + x0c], v11 = s[y1c * 32 + x1c];
    return (1.f - fy) * ((1.f - fx) * v00 + fx * v01) +
           fy * ((1.f - fx) * v10 + fx * v11);
}

// Fused NP passes of (2P+1)^2 zero-padded box blur, 64x64 output tile,
// sliding-origin scheme, SINGLE LDS buffer: H- and V-phase results are
// register-staged across a barrier then written back in place. LDS is
// halved vs two-buffer -> 4 blocks/CU (32 waves). All LDS access b128.
template <int P, int NP, bool UPS>
__global__ __launch_bounds__(512, 8) void blur_fused_kernel(
    const float* __restrict__ src, float* __restrict__ dst) {
    constexpr int T = 64;
    constexpr int HALO = NP * P;
    constexpr int BS = T + 2 * HALO;   // 84 (P=2) / 82 (P=3)
    constexpr int BW = 84;             // row stride words (mult of 4)
    constexpr float inv = 1.0f / (2 * P + 1);
    __shared__ float buf[BS * BW];
    __shared__ float cmb[UPS ? 1024 : 4];

    int tilex = blockIdx.x % 7;
    int tiley = (blockIdx.x / 7) % 7;
    int b = blockIdx.x / 49;
    int ox0 = tilex * T, oy0 = tiley * T;
    int tid = threadIdx.x;

    if (UPS) {
        const float* s = src + (size_t)b * NPATCH;
        for (int i = tid; i < NPATCH; i += 512) cmb[i] = s[i];
        __syncthreads();
        for (int i = tid; i < BS * BS; i += 512) {
            int r = i / BS, c = i % BS;
            int gy = oy0 + r - HALO, gx = ox0 + c - HALO;
            float v = 0.f;
            if (gy >= 0 && gy < H && gx >= 0 && gx < W) v = bilerp32(cmb, gy, gx);
            buf[r * BW + c] = v;
        }
    } else {
        const float* s = src + (size_t)b * HW;
        for (int i = tid; i < BS * BS; i += 512) {
            int r = i / BS, c = i % BS;
            int gy = oy0 + r - HALO, gx = ox0 + c - HALO;
            float v = 0.f;
            if (gy >= 0 && gy < H && gx >= 0 && gx < W) v = s[gy * W + gx];
            buf[r * BW + c] = v;
        }
    }
    __syncthreads();

#pragma unroll 1
    for (int pass = 0; pass < NP; ++pass) {
        const int S = BS - 2 * pass * P;
        const int wOut = S - 2 * P;
        const int ncell = (wOut + 3) >> 2;
        const int cellsH = S * ncell;
        float4 res[4];

        // H: res = avg_{j<=2P} buf[r][cc+j..]; write back in place after bar
#pragma unroll
        for (int k = 0; k < 4; ++k) {
            int i = tid + k * 512;
            int ic = i < cellsH ? i : cellsH - 1;
            int r = ic / ncell, cc = (ic % ncell) * 4;
            const float* bp = &buf[r * BW + cc];
            float4 A = *(const float4*)bp;
            float4 Bv = *(const float4*)(bp + 4);
            float o0, o1, o2, o3;
            if constexpr (P == 2) {
                float t = A.x + A.y + A.z + A.w + Bv.x;
                o0 = t;
                t += Bv.y - A.x; o1 = t;
                t += Bv.z - A.y; o2 = t;
                t += Bv.w - A.z; o3 = t;
            } else {
                float4 Cv = *(const float4*)(bp + 8);
                float t = A.x + A.y + A.z + A.w + Bv.x + Bv.y + Bv.z;
                o0 = t;
                t += Bv.w - A.x; o1 = t;
                t += Cv.x - A.y; o2 = t;
                t += Cv.y - A.z; o3 = t;
            }
            res[k] = make_float4(o0 * inv, o1 * inv, o2 * inv, o3 * inv);
        }
        __syncthreads();
#pragma unroll
        for (int k = 0; k < 4; ++k) {
            int i = tid + k * 512;
            if (i < cellsH) {
                int r = i / ncell, cc = (i % ncell) * 4;
                *(float4*)&buf[r * BW + cc] = res[k];
            }
        }
        __syncthreads();

        // V + out-of-image re-zero, register-staged the same way
        const int cellsV = wOut * ncell;
        const int org = (pass + 1) * P;
#pragma unroll
        for (int k = 0; k < 4; ++k) {
            int i = tid + k * 512;
            int ic = i < cellsV ? i : cellsV - 1;
            int r = ic / ncell, cc = (ic % ncell) * 4;
            float4 acc = *(const float4*)&buf[r * BW + cc];
#pragma unroll
            for (int j = 1; j <= 2 * P; ++j) {
                float4 v = *(const float4*)&buf[(r + j) * BW + cc];
                acc.x += v.x; acc.y += v.y; acc.z += v.z; acc.w += v.w;
            }
            int gy = oy0 - HALO + org + r;
            int gx = ox0 - HALO + org + cc;
            bool ry = (gy >= 0 && gy < H);
            float4 o;
            o.x = (ry && gx >= 0 && gx < W) ? acc.x * inv : 0.f;
            o.y = (ry && gx + 1 >= 0 && gx + 1 < W) ? acc.y * inv : 0.f;
            o.z = (ry && gx + 2 >= 0 && gx + 2 < W) ? acc.z * inv : 0.f;
            o.w = (ry && gx + 3 >= 0 && gx + 3 < W) ? acc.w * inv : 0.f;
            res[k] = o;
        }
        __syncthreads();
#pragma unroll
        for (int k = 0; k < 4; ++k) {
            int i = tid + k * 512;
            if (i < cellsV) {
                int r = i / ncell, cc = (i % ncell) * 4;
                *(float4*)&buf[r * BW + cc] = res[k];
            }
        }
        __syncthreads();
    }

    // buf[r][c] = output at (oy0+r, ox0+c), r,c in [0,64)
    float* d = dst + (size_t)b * HW;
    for (int i = tid; i < T * (T / 4); i += 512) {
        int r = i / (T / 4), cc = (i % (T / 4)) * 4;
        *(float4*)&d[(size_t)(oy0 + r) * W + ox0 + cc] =
            *(const float4*)&buf[r * BW + cc];
    }
}

// ---------------- grid-parallel exact top-k ----------------

__global__ __launch_bounds__(256) void hist_kernel(
    const float* __restrict__ map, unsigned* __restrict__ hist) {
    __shared__ unsigned lh[HBINS];
    int b = blockIdx.x / SLICES, sl = blockIdx.x % SLICES;
    for (int i = threadIdx.x; i < HBINS; i += 256) lh[i] = 0;
    __syncthreads();
    const uint4* u4 = (const uint4*)(map + (size_t)b * HW);
    int per4 = HW / SLICES / 4;  // 1568
    int start = sl * per4;
    for (int i = start + threadIdx.x; i < start + per4; i += 256) {
        uint4 v = u4[i];
        atomicAdd(&lh[v.x >> HSHIFT], 1u);
        atomicAdd(&lh[v.y >> HSHIFT], 1u);
        atomicAdd(&lh[v.z >> HSHIFT], 1u);
        atomicAdd(&lh[v.w >> HSHIFT], 1u);
    }
    __syncthreads();
    unsigned* gh = hist + (size_t)b * HBINS;
    for (int i = threadIdx.x; i < HBINS; i += 256) {
        unsigned c = lh[i];
        if (c) atomicAdd(&gh[i], c);
    }
}

__global__ __launch_bounds__(256) void select_kernel(
    const unsigned* __restrict__ hist, int* __restrict__ selbin) {
    int b = blockIdx.x;
    const unsigned* gh = hist + (size_t)b * HBINS;
    constexpr int CHUNK = HBINS / 256;  // 32
    __shared__ unsigned csum[256];
    int tid = threadIdx.x;
    unsigned s = 0;
#pragma unroll
    for (int j = 0; j < CHUNK; ++j) s += gh[tid * CHUNK + j];
    csum[tid] = s;
    __syncthreads();
    if (tid == 0) {
        unsigned acc = 0;
        int t = 255;
        for (; t > 0; --t) {
            if (acc + csum[t] >= TOPK) break;
            acc += csum[t];
        }
        int base = t * CHUNK;
        int j = CHUNK - 1;
        for (; j > 0; --j) {
            unsigned c = gh[base + j];
            if (acc + c >= TOPK) break;
            acc += c;
        }
        selbin[b * CSTRIDE] = base + j;
    }
}

__global__ __launch_bounds__(256) void compact_kernel(
    const float* __restrict__ map, const int* __restrict__ selbin,
    int* __restrict__ ccount, float* __restrict__ cand) {
    int tid = threadIdx.x;
    size_t base = (size_t)blockIdx.x * 1024;
    int b = (int)(base / HW);
    int sb = selbin[b * CSTRIDE];
    const uint4* u4 = (const uint4*)(((const unsigned*)map) + base);
    uint4 v = u4[tid];
    unsigned take0 = ((int)(v.x >> HSHIFT) >= sb);
    unsigned take1 = ((int)(v.y >> HSHIFT) >= sb);
    unsigned take2 = ((int)(v.z >> HSHIFT) >= sb);
    unsigned take3 = ((int)(v.w >> HSHIFT) >= sb);
    int c = (int)(take0 + take1 + take2 + take3);

    __shared__ int blkcnt, blkbase;
    if (tid == 0) blkcnt = 0;
    __syncthreads();
    int pos = 0;
    if (c) pos = atomicAdd(&blkcnt, c);
    __syncthreads();
    if (tid == 0 && blkcnt > 0)
        blkbase = atomicAdd(&ccount[b * CSTRIDE], blkcnt);
    __syncthreads();
    if (c) {
        float* o = cand + (size_t)b * HW + blkbase + pos;
        if (take0) *o++ = __uint_as_float(v.x);
        if (take1) *o++ = __uint_as_float(v.y);
        if (take2) *o++ = __uint_as_float(v.z);
        if (take3) *o = __uint_as_float(v.w);
    }
}

__global__ __launch_bounds__(256) void topk_kernel(
    const float* __restrict__ cand, const int* __restrict__ ccount,
    float* __restrict__ score) {
    int b = blockIdx.x;
    const float* s = cand + (size_t)b * HW;
    const unsigned* u = (const unsigned*)s;
    int M = ccount[b * CSTRIDE];
    __shared__ unsigned hist[256];
    __shared__ unsigned sh_prefix;
    __shared__ int sh_k;
    int tid = threadIdx.x;

    unsigned prefix = 0;
    int k = TOPK;
    for (int dgt = 3; dgt >= 0; --dgt) {
        hist[tid] = 0;
        __syncthreads();
        for (int i = tid; i < M; i += 256) {
            unsigned v = u[i];
            bool match;
            if (dgt == 3) match = true;
            else match = ((v >> (8 * (dgt + 1))) == prefix);
            if (match) atomicAdd(&hist[(v >> (8 * dgt)) & 255u], 1u);
        }
        __syncthreads();
        if (tid == 0) {
            int acc = 0;
            int j = 255;
            for (; j >= 0; --j) {
                acc += (int)hist[j];
                if (acc >= k) break;
            }
            sh_k = k - (acc - (int)hist[j]);
            sh_prefix = (prefix << 8) | (unsigned)j;
        }
        __syncthreads();
        prefix = sh_prefix;
        k = sh_k;
        __syncthreads();
    }

    float thr = __uint_as_float(prefix);
    float sum = 0.f;
    int cnt = 0;
    for (int i = tid; i < M; i += 256) {
        float v = s[i];
        if (v > thr) { sum += v; cnt++; }
    }
#pragma unroll
    for (int off = 32; off > 0; off >>= 1) {
        sum += __shfl_xor(sum, off);
        cnt += __shfl_xor(cnt, off);
    }
    __shared__ float wsum[4];
    __shared__ int wcnt[4];
    int wv = tid >> 6;
    if ((tid & 63) == 0) { wsum[wv] = sum; wcnt[wv] = cnt; }
    __syncthreads();
    if (tid == 0) {
        float s2 = 0.f;
        int c2 = 0;
        for (int i = 0; i < 4; ++i) { s2 += wsum[i]; c2 += wcnt[i]; }
        score[b] = (s2 + (float)(TOPK - c2) * thr) * (1.0f / TOPK);
    }
}

extern "C" void kernel_launch(void* const* d_in, const int* in_sizes, int n_in,
                              void* d_out, int out_size, void* d_ws, size_t ws_size,
                              hipStream_t stream) {
    const float* mid = (const float*)d_in[0];
    const float* last = (const float*)d_in[1];
    const float* pmid = (const float*)d_in[2];
    const float* plast = (const float*)d_in[3];
    int B = in_sizes[0] / (NPATCH * C);  // 16

    float* out_map = (float*)d_out;                   // B*448*448
    float* out_score = out_map + (size_t)B * HW;      // B

    float* combined = (float*)d_ws;
    int* meta = (int*)((char*)d_ws + 64 * 1024);
    int* ccount = meta;                               // [b*CSTRIDE]
    int* selbin = meta + 16 * CSTRIDE;                // [b*CSTRIDE]
    float* bufA = (float*)((char*)d_ws + 72 * 1024);  // B*HW floats
    unsigned* hist = (unsigned*)bufA;                 // overlays bufA
    float* cand = bufA;                               // overlays bufA

    int rows = B * NPATCH;
    anom_kernel<<<(rows + 3) / 4, 256, 0, stream>>>(mid, last, pmid, plast,
                                                    combined, rows);
    int nblk = B * 49;
    blur_fused_kernel<2, 5, true><<<nblk, 512, 0, stream>>>(combined, bufA);
    blur_fused_kernel<3, 3, false><<<nblk, 512, 0, stream>>>(bufA, out_map);

    // zero meta (8KB) + hist (512KB) in one contiguous async memset
    hipMemsetAsync((char*)d_ws + 64 * 1024, 0,
                   8192 + (size_t)B * HBINS * 4, stream);
    hist_kernel<<<B * SLICES, 256, 0, stream>>>(out_map, hist);
    select_kernel<<<B, 256, 0, stream>>>(hist, selbin);
    int nc = (B * HW) / 1024;
    compact_kernel<<<nc, 256, 0, stream>>>(out_map, selbin, ccount, cand);
    topk_kernel<<<B, 256, 0, stream>>>(cand, ccount, out_score);
}

// Round 8
// 167.238 us; speedup vs baseline: 1.2814x; 1.2814x over previous
//
#include <hip/hip_runtime.h>

constexpr int C = 768;
constexpr int NPATCH = 1024;   // (448/14)^2
constexpr int H = 448, W = 448;
constexpr int HW = H * W;      // 200704
constexpr int TOPK = 200;      // int(200704 * 0.001)
constexpr float EPS = 1e-12f;

constexpr int HBITS = 13;
constexpr int HBINS = 1 << HBITS;   // 8192
constexpr int HSHIFT = 18;          // bin = float_bits >> 18 (sign always 0)
constexpr int SLICES = 32;          // hist blocks per batch
constexpr int CSTRIDE = 64;         // ints between per-batch counters (256B)

typedef float f32x4 __attribute__((ext_vector_type(4)));

__device__ __forceinline__ float dotv(const f32x4 a, const f32x4 b) {
    return a.x * b.x + a.y * b.y + a.z * b.z + a.w * b.w;
}

// One wave per (b,n) row, nontemporal loads (bypass L2/L3 allocation path —
// measured: breaks the ~2.9 TB/s read plateau, anom ~70 -> ~20-25 us).
__global__ __launch_bounds__(256, 4) void anom_kernel(
    const float* __restrict__ m, const float* __restrict__ l,
    const float* __restrict__ pm, const float* __restrict__ pl,
    float* __restrict__ combined, int rows) {
    int wid = (int)((blockIdx.x * blockDim.x + threadIdx.x) >> 6);
    int lane = threadIdx.x & 63;
    if (wid >= rows) return;
    size_t base = (size_t)wid * C;
    const f32x4* A = (const f32x4*)(m + base);
    const f32x4* B = (const f32x4*)(pm + base);
    const f32x4* Cc = (const f32x4*)(l + base);
    const f32x4* D = (const f32x4*)(pl + base);

    f32x4 a0 = __builtin_nontemporal_load(A + lane);
    f32x4 a1 = __builtin_nontemporal_load(A + lane + 64);
    f32x4 a2 = __builtin_nontemporal_load(A + lane + 128);
    f32x4 b0 = __builtin_nontemporal_load(B + lane);
    f32x4 b1 = __builtin_nontemporal_load(B + lane + 64);
    f32x4 b2 = __builtin_nontemporal_load(B + lane + 128);
    f32x4 c0 = __builtin_nontemporal_load(Cc + lane);
    f32x4 c1 = __builtin_nontemporal_load(Cc + lane + 64);
    f32x4 c2 = __builtin_nontemporal_load(Cc + lane + 128);
    f32x4 d0 = __builtin_nontemporal_load(D + lane);
    f32x4 d1 = __builtin_nontemporal_load(D + lane + 64);
    f32x4 d2 = __builtin_nontemporal_load(D + lane + 128);

    float mm = dotv(a0, a0) + dotv(a1, a1) + dotv(a2, a2);
    float pp = dotv(b0, b0) + dotv(b1, b1) + dotv(b2, b2);
    float mp = dotv(a0, b0) + dotv(a1, b1) + dotv(a2, b2);
    float ll = dotv(c0, c0) + dotv(c1, c1) + dotv(c2, c2);
    float qq = dotv(d0, d0) + dotv(d1, d1) + dotv(d2, d2);
    float lq = dotv(c0, d0) + dotv(c1, d1) + dotv(c2, d2);

#pragma unroll
    for (int off = 32; off > 0; off >>= 1) {
        mm += __shfl_xor(mm, off);
        pp += __shfl_xor(pp, off);
        mp += __shfl_xor(mp, off);
        ll += __shfl_xor(ll, off);
        qq += __shfl_xor(qq, off);
        lq += __shfl_xor(lq, off);
    }
    if (lane == 0) {
        float rm = 1.0f / fmaxf(sqrtf(mm), EPS);
        float rp = 1.0f / fmaxf(sqrtf(pp), EPS);
        float rl = 1.0f / fmaxf(sqrtf(ll), EPS);
        float rq = 1.0f / fmaxf(sqrtf(qq), EPS);
        float d2m = fmaxf(mm * rm * rm - 2.f * mp * rm * rp + pp * rp * rp, 0.f);
        float d2l = fmaxf(ll * rl * rl - 2.f * lq * rl * rq + qq * rq * rq, 0.f);
        combined[wid] = sqrtf(d2m) * sqrtf(d2l);
    }
}

__device__ __forceinline__ float bilerp32(const float* __restrict__ s,
                                          int gy, int gx) {
    float sx = (gx + 0.5f) * (1.0f / 14.0f) - 0.5f;
    float sy = (gy + 0.5f) * (1.0f / 14.0f) - 0.5f;
    float fx0 = floorf(sx), fy0 = floorf(sy);
    float fx = sx - fx0, fy = sy - fy0;
    int x0 = (int)fx0, y0 = (int)fy0;
    int x0c = min(max(x0, 0), 31);
    int x1c = min(max(x0 + 1, 0), 31);
    int y0c = min(max(y0, 0), 31);
    int y1c = min(max(y0 + 1, 0), 31);
    float v00 = s[y0c * 32 + x0c], v01 = s[y0c * 32 + x1c];
    float v10 = s[y1c * 32 + x0c], v11 = s[y1c * 32 + x1c];
    return (1.f - fy) * ((1.f - fx) * v00 + fx * v01) +
           fy * ((1.f - fx) * v10 + fx * v11);
}

// Fused NP passes of (2P+1)^2 zero-padded box blur, 64x64 output tile,
// sliding-origin LDS scheme, TWO buffers (proven ~37us config from R4);
// all LDS access is b128.
template <int P, int NP, bool UPS>
__global__ __launch_bounds__(512) void blur_fused_kernel(
    const float* __restrict__ src, float* __restrict__ dst) {
    constexpr int T = 64;
    constexpr int HALO = NP * P;
    constexpr int BS = T + 2 * HALO;   // 84 (P2) / 82 (P3)
    constexpr int BW = 84;             // row stride (words), mult of 4
    constexpr float inv = 1.0f / (2 * P + 1);
    __shared__ float buf[BS * BW];
    __shared__ float tmp[84 * BW];

    int tilex = blockIdx.x % 7;
    int tiley = (blockIdx.x / 7) % 7;
    int b = blockIdx.x / 49;
    int ox0 = tilex * T, oy0 = tiley * T;
    int tid = threadIdx.x;

    if (UPS) {
        const float* s = src + (size_t)b * NPATCH;
        for (int i = tid; i < NPATCH; i += 512) tmp[i] = s[i];
        __syncthreads();
        for (int i = tid; i < BS * BS; i += 512) {
            int r = i / BS, c = i % BS;
            int gy = oy0 + r - HALO, gx = ox0 + c - HALO;
            float v = 0.f;
            if (gy >= 0 && gy < H && gx >= 0 && gx < W) v = bilerp32(tmp, gy, gx);
            buf[r * BW + c] = v;
        }
    } else {
        const float* s = src + (size_t)b * HW;
        for (int i = tid; i < BS * BS; i += 512) {
            int r = i / BS, c = i % BS;
            int gy = oy0 + r - HALO, gx = ox0 + c - HALO;
            float v = 0.f;
            if (gy >= 0 && gy < H && gx >= 0 && gx < W) v = s[gy * W + gx];
            buf[r * BW + c] = v;
        }
    }
    __syncthreads();

#pragma unroll 1
    for (int pass = 0; pass < NP; ++pass) {
        int S = BS - 2 * pass * P;
        int wOut = S - 2 * P;
        int ncell = (wOut + 3) >> 2;
        int cellsH = S * ncell;
        for (int i = tid; i < cellsH; i += 512) {
            int r = i / ncell, cc = (i % ncell) * 4;
            const float* bp = &buf[r * BW + cc];
            float4 A = *(const float4*)bp;
            float4 Bv = *(const float4*)(bp + 4);
            float o0, o1, o2, o3;
            if (P == 2) {
                float t = A.x + A.y + A.z + A.w + Bv.x;
                o0 = t;
                t += Bv.y - A.x; o1 = t;
                t += Bv.z - A.y; o2 = t;
                t += Bv.w - A.z; o3 = t;
            } else {
                float4 Cv = *(const float4*)(bp + 8);
                float t = A.x + A.y + A.z + A.w + Bv.x + Bv.y + Bv.z;
                o0 = t;
                t += Bv.w - A.x; o1 = t;
                t += Cv.x - A.y; o2 = t;
                t += Cv.y - A.z; o3 = t;
            }
            *(float4*)&tmp[r * BW + cc] =
                make_float4(o0 * inv, o1 * inv, o2 * inv, o3 * inv);
        }
        __syncthreads();
        int org = (pass + 1) * P;
        int cellsV = wOut * ncell;
        for (int i = tid; i < cellsV; i += 512) {
            int r = i / ncell, cc = (i % ncell) * 4;
            float4 acc = *(const float4*)&tmp[r * BW + cc];
#pragma unroll
            for (int j = 1; j <= 2 * P; ++j) {
                float4 v = *(const float4*)&tmp[(r + j) * BW + cc];
                acc.x += v.x; acc.y += v.y; acc.z += v.z; acc.w += v.w;
            }
            int gy = oy0 - HALO + org + r;
            int gx = ox0 - HALO + org + cc;
            bool ry = (gy >= 0 && gy < H);
            float4 o;
            o.x = (ry && gx >= 0 && gx < W) ? acc.x * inv : 0.f;
            o.y = (ry && gx + 1 >= 0 && gx + 1 < W) ? acc.y * inv : 0.f;
            o.z = (ry && gx + 2 >= 0 && gx + 2 < W) ? acc.z * inv : 0.f;
            o.w = (ry && gx + 3 >= 0 && gx + 3 < W) ? acc.w * inv : 0.f;
            *(float4*)&buf[r * BW + cc] = o;
        }
        __syncthreads();
    }

    float* d = dst + (size_t)b * HW;
    for (int i = tid; i < T * (T / 4); i += 512) {
        int r = i / (T / 4), cc = (i % (T / 4)) * 4;
        *(float4*)&d[(size_t)(oy0 + r) * W + ox0 + cc] =
            *(const float4*)&buf[r * BW + cc];
    }
}

// ---------------- grid-parallel exact top-k ----------------

__global__ __launch_bounds__(256) void hist_kernel(
    const float* __restrict__ map, unsigned* __restrict__ hist) {
    __shared__ unsigned lh[HBINS];
    int b = blockIdx.x / SLICES, sl = blockIdx.x % SLICES;
    for (int i = threadIdx.x; i < HBINS; i += 256) lh[i] = 0;
    __syncthreads();
    const uint4* u4 = (const uint4*)(map + (size_t)b * HW);
    int per4 = HW / SLICES / 4;  // 1568
    int start = sl * per4;
    for (int i = start + threadIdx.x; i < start + per4; i += 256) {
        uint4 v = u4[i];
        atomicAdd(&lh[v.x >> HSHIFT], 1u);
        atomicAdd(&lh[v.y >> HSHIFT], 1u);
        atomicAdd(&lh[v.z >> HSHIFT], 1u);
        atomicAdd(&lh[v.w >> HSHIFT], 1u);
    }
    __syncthreads();
    unsigned* gh = hist + (size_t)b * HBINS;
    for (int i = threadIdx.x; i < HBINS; i += 256) {
        unsigned c = lh[i];
        if (c) atomicAdd(&gh[i], c);
    }
}

__global__ __launch_bounds__(256) void select_kernel(
    const unsigned* __restrict__ hist, int* __restrict__ selbin) {
    int b = blockIdx.x;
    const unsigned* gh = hist + (size_t)b * HBINS;
    constexpr int CHUNK = HBINS / 256;  // 32
    __shared__ unsigned csum[256];
    int tid = threadIdx.x;
    unsigned s = 0;
#pragma unroll
    for (int j = 0; j < CHUNK; ++j) s += gh[tid * CHUNK + j];
    csum[tid] = s;
    __syncthreads();
    if (tid == 0) {
        unsigned acc = 0;
        int t = 255;
        for (; t > 0; --t) {
            if (acc + csum[t] >= TOPK) break;
            acc += csum[t];
        }
        int base = t * CHUNK;
        int j = CHUNK - 1;
        for (; j > 0; --j) {
            unsigned c = gh[base + j];
            if (acc + c >= TOPK) break;
            acc += c;
        }
        selbin[b * CSTRIDE] = base + j;
    }
}

__global__ __launch_bounds__(256) void compact_kernel(
    const float* __restrict__ map, const int* __restrict__ selbin,
    int* __restrict__ ccount, float* __restrict__ cand) {
    int tid = threadIdx.x;
    size_t base = (size_t)blockIdx.x * 1024;
    int b = (int)(base / HW);
    int sb = selbin[b * CSTRIDE];
    const uint4* u4 = (const uint4*)(((const unsigned*)map) + base);
    uint4 v = u4[tid];
    unsigned take0 = ((int)(v.x >> HSHIFT) >= sb);
    unsigned take1 = ((int)(v.y >> HSHIFT) >= sb);
    unsigned take2 = ((int)(v.z >> HSHIFT) >= sb);
    unsigned take3 = ((int)(v.w >> HSHIFT) >= sb);
    int c = (int)(take0 + take1 + take2 + take3);

    __shared__ int blkcnt, blkbase;
    if (tid == 0) blkcnt = 0;
    __syncthreads();
    int pos = 0;
    if (c) pos = atomicAdd(&blkcnt, c);
    __syncthreads();
    if (tid == 0 && blkcnt > 0)
        blkbase = atomicAdd(&ccount[b * CSTRIDE], blkcnt);
    __syncthreads();
    if (c) {
        float* o = cand + (size_t)b * HW + blkbase + pos;
        if (take0) *o++ = __uint_as_float(v.x);
        if (take1) *o++ = __uint_as_float(v.y);
        if (take2) *o++ = __uint_as_float(v.z);
        if (take3) *o = __uint_as_float(v.w);
    }
}

__global__ __launch_bounds__(256) void topk_kernel(
    const float* __restrict__ cand, const int* __restrict__ ccount,
    float* __restrict__ score) {
    int b = blockIdx.x;
    const float* s = cand + (size_t)b * HW;
    const unsigned* u = (const unsigned*)s;
    int M = ccount[b * CSTRIDE];
    __shared__ unsigned hist[256];
    __shared__ unsigned sh_prefix;
    __shared__ int sh_k;
    int tid = threadIdx.x;

    unsigned prefix = 0;
    int k = TOPK;
    for (int dgt = 3; dgt >= 0; --dgt) {
        hist[tid] = 0;
        __syncthreads();
        for (int i = tid; i < M; i += 256) {
            unsigned v = u[i];
            bool match;
            if (dgt == 3) match = true;
            else match = ((v >> (8 * (dgt + 1))) == prefix);
            if (match) atomicAdd(&hist[(v >> (8 * dgt)) & 255u], 1u);
        }
        __syncthreads();
        if (tid == 0) {
            int acc = 0;
            int j = 255;
            for (; j >= 0; --j) {
                acc += (int)hist[j];
                if (acc >= k) break;
            }
            sh_k = k - (acc - (int)hist[j]);
            sh_prefix = (prefix << 8) | (unsigned)j;
        }
        __syncthreads();
        prefix = sh_prefix;
        k = sh_k;
        __syncthreads();
    }

    float thr = __uint_as_float(prefix);
    float sum = 0.f;
    int cnt = 0;
    for (int i = tid; i < M; i += 256) {
        float v = s[i];
        if (v > thr) { sum += v; cnt++; }
    }
#pragma unroll
    for (int off = 32; off > 0; off >>= 1) {
        sum += __shfl_xor(sum, off);
        cnt += __shfl_xor(cnt, off);
    }
    __shared__ float wsum[4];
    __shared__ int wcnt[4];
    int wv = tid >> 6;
    if ((tid & 63) == 0) { wsum[wv] = sum; wcnt[wv] = cnt; }
    __syncthreads();
    if (tid == 0) {
        float s2 = 0.f;
        int c2 = 0;
        for (int i = 0; i < 4; ++i) { s2 += wsum[i]; c2 += wcnt[i]; }
        score[b] = (s2 + (float)(TOPK - c2) * thr) * (1.0f / TOPK);
    }
}

extern "C" void kernel_launch(void* const* d_in, const int* in_sizes, int n_in,
                              void* d_out, int out_size, void* d_ws, size_t ws_size,
                              hipStream_t stream) {
    const float* mid = (const float*)d_in[0];
    const float* last = (const float*)d_in[1];
    const float* pmid = (const float*)d_in[2];
    const float* plast = (const float*)d_in[3];
    int B = in_sizes[0] / (NPATCH * C);  // 16

    float* out_map = (float*)d_out;                   // B*448*448
    float* out_score = out_map + (size_t)B * HW;      // B

    float* combined = (float*)d_ws;
    int* meta = (int*)((char*)d_ws + 64 * 1024);
    int* ccount = meta;                               // [b*CSTRIDE]
    int* selbin = meta + 16 * CSTRIDE;                // [b*CSTRIDE]
    float* bufA = (float*)((char*)d_ws + 72 * 1024);  // B*HW floats
    unsigned* hist = (unsigned*)bufA;                 // overlays bufA
    float* cand = bufA;                               // overlays bufA

    int rows = B * NPATCH;
    anom_kernel<<<(rows + 3) / 4, 256, 0, stream>>>(mid, last, pmid, plast,
                                                    combined, rows);
    int nblk = B * 49;
    blur_fused_kernel<2, 5, true><<<nblk, 512, 0, stream>>>(combined, bufA);
    blur_fused_kernel<3, 3, false><<<nblk, 512, 0, stream>>>(bufA, out_map);

    // zero meta (8KB) + hist (512KB) in one contiguous async memset
    hipMemsetAsync((char*)d_ws + 64 * 1024, 0,
                   8192 + (size_t)B * HBINS * 4, stream);
    hist_kernel<<<B * SLICES, 256, 0, stream>>>(out_map, hist);
    select_kernel<<<B, 256, 0, stream>>>(hist, selbin);
    int nc = (B * HW) / 1024;
    compact_kernel<<<nc, 256, 0, stream>>>(out_map, selbin, ccount, cand);
    topk_kernel<<<B, 256, 0, stream>>>(cand, ccount, out_score);
}

// Round 9
// 128.015 us; speedup vs baseline: 1.6740x; 1.3064x over previous
//
#include <hip/hip_runtime.h>

constexpr int C = 768;
constexpr int NPATCH = 1024;   // (448/14)^2
constexpr int H = 448, W = 448;
constexpr int HW = H * W;      // 200704
constexpr int TOPK = 200;      // int(200704 * 0.001)
constexpr float EPS = 1e-12f;

constexpr int HBITS = 13;
constexpr int HBINS = 1 << HBITS;   // 8192
constexpr int HSHIFT = 18;          // bin = float_bits >> 18 (sign always 0)
constexpr int SLICES = 32;          // hist blocks per batch
constexpr int CSTRIDE = 64;         // ints between per-batch counters (256B)

typedef float f32x4 __attribute__((ext_vector_type(4)));

__device__ __forceinline__ float dotv(const f32x4 a, const f32x4 b) {
    return a.x * b.x + a.y * b.y + a.z * b.z + a.w * b.w;
}

// One wave per (b,n) row, nontemporal loads (bypass L2/L3 allocation path —
// measured: breaks the ~2.9 TB/s read plateau, anom ~70 -> ~20-25 us).
__global__ __launch_bounds__(256, 4) void anom_kernel(
    const float* __restrict__ m, const float* __restrict__ l,
    const float* __restrict__ pm, const float* __restrict__ pl,
    float* __restrict__ combined, int rows) {
    int wid = (int)((blockIdx.x * blockDim.x + threadIdx.x) >> 6);
    int lane = threadIdx.x & 63;
    if (wid >= rows) return;
    size_t base = (size_t)wid * C;
    const f32x4* A = (const f32x4*)(m + base);
    const f32x4* B = (const f32x4*)(pm + base);
    const f32x4* Cc = (const f32x4*)(l + base);
    const f32x4* D = (const f32x4*)(pl + base);

    f32x4 a0 = __builtin_nontemporal_load(A + lane);
    f32x4 a1 = __builtin_nontemporal_load(A + lane + 64);
    f32x4 a2 = __builtin_nontemporal_load(A + lane + 128);
    f32x4 b0 = __builtin_nontemporal_load(B + lane);
    f32x4 b1 = __builtin_nontemporal_load(B + lane + 64);
    f32x4 b2 = __builtin_nontemporal_load(B + lane + 128);
    f32x4 c0 = __builtin_nontemporal_load(Cc + lane);
    f32x4 c1 = __builtin_nontemporal_load(Cc + lane + 64);
    f32x4 c2 = __builtin_nontemporal_load(Cc + lane + 128);
    f32x4 d0 = __builtin_nontemporal_load(D + lane);
    f32x4 d1 = __builtin_nontemporal_load(D + lane + 64);
    f32x4 d2 = __builtin_nontemporal_load(D + lane + 128);

    float mm = dotv(a0, a0) + dotv(a1, a1) + dotv(a2, a2);
    float pp = dotv(b0, b0) + dotv(b1, b1) + dotv(b2, b2);
    float mp = dotv(a0, b0) + dotv(a1, b1) + dotv(a2, b2);
    float ll = dotv(c0, c0) + dotv(c1, c1) + dotv(c2, c2);
    float qq = dotv(d0, d0) + dotv(d1, d1) + dotv(d2, d2);
    float lq = dotv(c0, d0) + dotv(c1, d1) + dotv(c2, d2);

#pragma unroll
    for (int off = 32; off > 0; off >>= 1) {
        mm += __shfl_xor(mm, off);
        pp += __shfl_xor(pp, off);
        mp += __shfl_xor(mp, off);
        ll += __shfl_xor(ll, off);
        qq += __shfl_xor(qq, off);
        lq += __shfl_xor(lq, off);
    }
    if (lane == 0) {
        float rm = 1.0f / fmaxf(sqrtf(mm), EPS);
        float rp = 1.0f / fmaxf(sqrtf(pp), EPS);
        float rl = 1.0f / fmaxf(sqrtf(ll), EPS);
        float rq = 1.0f / fmaxf(sqrtf(qq), EPS);
        float d2m = fmaxf(mm * rm * rm - 2.f * mp * rm * rp + pp * rp * rp, 0.f);
        float d2l = fmaxf(ll * rl * rl - 2.f * lq * rl * rq + qq * rq * rq, 0.f);
        combined[wid] = sqrtf(d2m) * sqrtf(d2l);
    }
}

__device__ __forceinline__ float bilerp32(const float* __restrict__ s,
                                          int gy, int gx) {
    float sx = (gx + 0.5f) * (1.0f / 14.0f) - 0.5f;
    float sy = (gy + 0.5f) * (1.0f / 14.0f) - 0.5f;
    float fx0 = floorf(sx), fy0 = floorf(sy);
    float fx = sx - fx0, fy = sy - fy0;
    int x0 = (int)fx0, y0 = (int)fy0;
    int x0c = min(max(x0, 0), 31);
    int x1c = min(max(x0 + 1, 0), 31);
    int y0c = min(max(y0, 0), 31);
    int y1c = min(max(y0 + 1, 0), 31);
    float v00 = s[y0c * 32 + x0c], v01 = s[y0c * 32 + x1c];
    float v10 = s[y1c * 32 + x0c], v11 = s[y1c * 32 + x1c];
    return (1.f - fy) * ((1.f - fx) * v00 + fx * v01) +
           fy * ((1.f - fx) * v10 + fx * v11);
}

// Fused NP passes of (2P+1)^2 zero-padded box blur, 64x64 output tile,
// sliding-origin LDS scheme, TWO buffers (proven config); all LDS b128.
template <int P, int NP, bool UPS>
__global__ __launch_bounds__(512) void blur_fused_kernel(
    const float* __restrict__ src, float* __restrict__ dst) {
    constexpr int T = 64;
    constexpr int HALO = NP * P;
    constexpr int BS = T + 2 * HALO;   // 84 (P2) / 82 (P3)
    constexpr int BW = 84;             // row stride (words), mult of 4
    constexpr float inv = 1.0f / (2 * P + 1);
    __shared__ float buf[BS * BW];
    __shared__ float tmp[84 * BW];

    int tilex = blockIdx.x % 7;
    int tiley = (blockIdx.x / 7) % 7;
    int b = blockIdx.x / 49;
    int ox0 = tilex * T, oy0 = tiley * T;
    int tid = threadIdx.x;

    if (UPS) {
        const float* s = src + (size_t)b * NPATCH;
        for (int i = tid; i < NPATCH; i += 512) tmp[i] = s[i];
        __syncthreads();
        for (int i = tid; i < BS * BS; i += 512) {
            int r = i / BS, c = i % BS;
            int gy = oy0 + r - HALO, gx = ox0 + c - HALO;
            float v = 0.f;
            if (gy >= 0 && gy < H && gx >= 0 && gx < W) v = bilerp32(tmp, gy, gx);
            buf[r * BW + c] = v;
        }
    } else {
        const float* s = src + (size_t)b * HW;
        for (int i = tid; i < BS * BS; i += 512) {
            int r = i / BS, c = i % BS;
            int gy = oy0 + r - HALO, gx = ox0 + c - HALO;
            float v = 0.f;
            if (gy >= 0 && gy < H && gx >= 0 && gx < W) v = s[gy * W + gx];
            buf[r * BW + c] = v;
        }
    }
    __syncthreads();

#pragma unroll 1
    for (int pass = 0; pass < NP; ++pass) {
        int S = BS - 2 * pass * P;
        int wOut = S - 2 * P;
        int ncell = (wOut + 3) >> 2;
        int cellsH = S * ncell;
        for (int i = tid; i < cellsH; i += 512) {
            int r = i / ncell, cc = (i % ncell) * 4;
            const float* bp = &buf[r * BW + cc];
            float4 A = *(const float4*)bp;
            float4 Bv = *(const float4*)(bp + 4);
            float o0, o1, o2, o3;
            if (P == 2) {
                float t = A.x + A.y + A.z + A.w + Bv.x;
                o0 = t;
                t += Bv.y - A.x; o1 = t;
                t += Bv.z - A.y; o2 = t;
                t += Bv.w - A.z; o3 = t;
            } else {
                float4 Cv = *(const float4*)(bp + 8);
                float t = A.x + A.y + A.z + A.w + Bv.x + Bv.y + Bv.z;
                o0 = t;
                t += Bv.w - A.x; o1 = t;
                t += Cv.x - A.y; o2 = t;
                t += Cv.y - A.z; o3 = t;
            }
            *(float4*)&tmp[r * BW + cc] =
                make_float4(o0 * inv, o1 * inv, o2 * inv, o3 * inv);
        }
        __syncthreads();
        int org = (pass + 1) * P;
        int cellsV = wOut * ncell;
        for (int i = tid; i < cellsV; i += 512) {
            int r = i / ncell, cc = (i % ncell) * 4;
            float4 acc = *(const float4*)&tmp[r * BW + cc];
#pragma unroll
            for (int j = 1; j <= 2 * P; ++j) {
                float4 v = *(const float4*)&tmp[(r + j) * BW + cc];
                acc.x += v.x; acc.y += v.y; acc.z += v.z; acc.w += v.w;
            }
            int gy = oy0 - HALO + org + r;
            int gx = ox0 - HALO + org + cc;
            bool ry = (gy >= 0 && gy < H);
            float4 o;
            o.x = (ry && gx >= 0 && gx < W) ? acc.x * inv : 0.f;
            o.y = (ry && gx + 1 >= 0 && gx + 1 < W) ? acc.y * inv : 0.f;
            o.z = (ry && gx + 2 >= 0 && gx + 2 < W) ? acc.z * inv : 0.f;
            o.w = (ry && gx + 3 >= 0 && gx + 3 < W) ? acc.w * inv : 0.f;
            *(float4*)&buf[r * BW + cc] = o;
        }
        __syncthreads();
    }

    float* d = dst + (size_t)b * HW;
    for (int i = tid; i < T * (T / 4); i += 512) {
        int r = i / (T / 4), cc = (i % (T / 4)) * 4;
        *(float4*)&d[(size_t)(oy0 + r) * W + ox0 + cc] =
            *(const float4*)&buf[r * BW + cc];
    }
}

// ---------------- grid-parallel exact top-k ----------------

__global__ __launch_bounds__(256) void hist_kernel(
    const float* __restrict__ map, unsigned* __restrict__ hist) {
    __shared__ unsigned lh[HBINS];
    int b = blockIdx.x / SLICES, sl = blockIdx.x % SLICES;
    for (int i = threadIdx.x; i < HBINS; i += 256) lh[i] = 0;
    __syncthreads();
    const uint4* u4 = (const uint4*)(map + (size_t)b * HW);
    int per4 = HW / SLICES / 4;  // 1568
    int start = sl * per4;
    for (int i = start + threadIdx.x; i < start + per4; i += 256) {
        uint4 v = u4[i];
        atomicAdd(&lh[v.x >> HSHIFT], 1u);
        atomicAdd(&lh[v.y >> HSHIFT], 1u);
        atomicAdd(&lh[v.z >> HSHIFT], 1u);
        atomicAdd(&lh[v.w >> HSHIFT], 1u);
    }
    __syncthreads();
    unsigned* gh = hist + (size_t)b * HBINS;
    for (int i = threadIdx.x; i < HBINS; i += 256) {
        unsigned c = lh[i];
        if (c) atomicAdd(&gh[i], c);
    }
}

// Parallel suffix-scan select: largest bin with count(bins >= bin) >= TOPK.
__global__ __launch_bounds__(256) void select_kernel(
    const unsigned* __restrict__ hist, int* __restrict__ selbin) {
    int b = blockIdx.x;
    const unsigned* gh = hist + (size_t)b * HBINS;
    constexpr int CHUNK = HBINS / 256;  // 32
    __shared__ unsigned ss[257];
    __shared__ unsigned cs2[33];
    __shared__ int sh_base, sh_k;
    int tid = threadIdx.x;
    unsigned s = 0;
#pragma unroll
    for (int j = 0; j < CHUNK; ++j) s += gh[tid * CHUNK + j];
    ss[tid] = s;
    if (tid == 0) ss[256] = 0;
    __syncthreads();
#pragma unroll
    for (int st = 1; st < 256; st <<= 1) {
        unsigned add = (tid + st < 256) ? ss[tid + st] : 0u;
        __syncthreads();
        ss[tid] += add;
        __syncthreads();
    }
    if ((int)ss[tid] >= TOPK && (int)ss[tid + 1] < TOPK) {
        sh_base = tid * CHUNK;
        sh_k = TOPK - (int)ss[tid + 1];
    }
    __syncthreads();
    int base = sh_base, kk = sh_k;
    if (tid < 32) cs2[tid] = gh[base + tid];
    if (tid == 0) cs2[32] = 0;
    __syncthreads();
#pragma unroll
    for (int st = 1; st < 32; st <<= 1) {
        unsigned add = (tid < 32 && tid + st < 32) ? cs2[tid + st] : 0u;
        __syncthreads();
        if (tid < 32) cs2[tid] += add;
        __syncthreads();
    }
    if (tid < 32 && (int)cs2[tid] >= kk && (int)cs2[tid + 1] < kk)
        selbin[b * CSTRIDE] = base + tid;
}

__global__ __launch_bounds__(256) void compact_kernel(
    const float* __restrict__ map, const int* __restrict__ selbin,
    int* __restrict__ ccount, float* __restrict__ cand) {
    int tid = threadIdx.x;
    size_t base = (size_t)blockIdx.x * 1024;
    int b = (int)(base / HW);
    int sb = selbin[b * CSTRIDE];
    const uint4* u4 = (const uint4*)(((const unsigned*)map) + base);
    uint4 v = u4[tid];
    unsigned take0 = ((int)(v.x >> HSHIFT) >= sb);
    unsigned take1 = ((int)(v.y >> HSHIFT) >= sb);
    unsigned take2 = ((int)(v.z >> HSHIFT) >= sb);
    unsigned take3 = ((int)(v.w >> HSHIFT) >= sb);
    int c = (int)(take0 + take1 + take2 + take3);

    __shared__ int blkcnt, blkbase;
    if (tid == 0) blkcnt = 0;
    __syncthreads();
    int pos = 0;
    if (c) pos = atomicAdd(&blkcnt, c);
    __syncthreads();
    if (tid == 0 && blkcnt > 0)
        blkbase = atomicAdd(&ccount[b * CSTRIDE], blkcnt);
    __syncthreads();
    if (c) {
        float* o = cand + (size_t)b * HW + blkbase + pos;
        if (take0) *o++ = __uint_as_float(v.x);
        if (take1) *o++ = __uint_as_float(v.y);
        if (take2) *o++ = __uint_as_float(v.z);
        if (take3) *o = __uint_as_float(v.w);
    }
}

// Exact top-200 mean via radix select over candidates; per-digit bin scan
// is a parallel suffix-sum (was a 256-iter serial LDS chain = 43 us).
__global__ __launch_bounds__(256) void topk_kernel(
    const float* __restrict__ cand, const int* __restrict__ ccount,
    float* __restrict__ score) {
    int b = blockIdx.x;
    const float* s = cand + (size_t)b * HW;
    const unsigned* u = (const unsigned*)s;
    int M = ccount[b * CSTRIDE];
    __shared__ unsigned hist[256];
    __shared__ unsigned ss[257];
    __shared__ unsigned sh_prefix;
    __shared__ int sh_k;
    int tid = threadIdx.x;

    unsigned prefix = 0;
    int k = TOPK;
    for (int dgt = 3; dgt >= 0; --dgt) {
        hist[tid] = 0;
        __syncthreads();
        for (int i = tid; i < M; i += 256) {
            unsigned v = u[i];
            bool match = (dgt == 3) || ((v >> (8 * (dgt + 1))) == prefix);
            if (match) atomicAdd(&hist[(v >> (8 * dgt)) & 255u], 1u);
        }
        __syncthreads();
        ss[tid] = hist[tid];
        if (tid == 0) ss[256] = 0;
        __syncthreads();
#pragma unroll
        for (int st = 1; st < 256; st <<= 1) {
            unsigned add = (tid + st < 256) ? ss[tid + st] : 0u;
            __syncthreads();
            ss[tid] += add;
            __syncthreads();
        }
        if ((int)ss[tid] >= k && (int)ss[tid + 1] < k) {
            sh_prefix = (prefix << 8) | (unsigned)tid;
            sh_k = k - (int)ss[tid + 1];
        }
        __syncthreads();
        prefix = sh_prefix;
        k = sh_k;
        __syncthreads();
    }

    float thr = __uint_as_float(prefix);
    float sum = 0.f;
    int cnt = 0;
    for (int i = tid; i < M; i += 256) {
        float v = s[i];
        if (v > thr) { sum += v; cnt++; }
    }
#pragma unroll
    for (int off = 32; off > 0; off >>= 1) {
        sum += __shfl_xor(sum, off);
        cnt += __shfl_xor(cnt, off);
    }
    __shared__ float wsum[4];
    __shared__ int wcnt[4];
    int wv = tid >> 6;
    if ((tid & 63) == 0) { wsum[wv] = sum; wcnt[wv] = cnt; }
    __syncthreads();
    if (tid == 0) {
        float s2 = 0.f;
        int c2 = 0;
        for (int i = 0; i < 4; ++i) { s2 += wsum[i]; c2 += wcnt[i]; }
        score[b] = (s2 + (float)(TOPK - c2) * thr) * (1.0f / TOPK);
    }
}

extern "C" void kernel_launch(void* const* d_in, const int* in_sizes, int n_in,
                              void* d_out, int out_size, void* d_ws, size_t ws_size,
                              hipStream_t stream) {
    const float* mid = (const float*)d_in[0];
    const float* last = (const float*)d_in[1];
    const float* pmid = (const float*)d_in[2];
    const float* plast = (const float*)d_in[3];
    int B = in_sizes[0] / (NPATCH * C);  // 16

    float* out_map = (float*)d_out;                   // B*448*448
    float* out_score = out_map + (size_t)B * HW;      // B

    float* combined = (float*)d_ws;
    int* meta = (int*)((char*)d_ws + 64 * 1024);
    int* ccount = meta;                               // [b*CSTRIDE]
    int* selbin = meta + 16 * CSTRIDE;                // [b*CSTRIDE]
    float* bufA = (float*)((char*)d_ws + 72 * 1024);  // B*HW floats
    unsigned* hist = (unsigned*)bufA;                 // overlays bufA
    float* cand = bufA;                               // overlays bufA

    int rows = B * NPATCH;
    anom_kernel<<<(rows + 3) / 4, 256, 0, stream>>>(mid, last, pmid, plast,
                                                    combined, rows);
    int nblk = B * 49;
    blur_fused_kernel<2, 5, true><<<nblk, 512, 0, stream>>>(combined, bufA);
    blur_fused_kernel<3, 3, false><<<nblk, 512, 0, stream>>>(bufA, out_map);

    // zero meta (8KB) + hist (512KB) in one contiguous async memset
    hipMemsetAsync((char*)d_ws + 64 * 1024, 0,
                   8192 + (size_t)B * HBINS * 4, stream);
    hist_kernel<<<B * SLICES, 256, 0, stream>>>(out_map, hist);
    select_kernel<<<B, 256, 0, stream>>>(hist, selbin);
    int nc = (B * HW) / 1024;
    compact_kernel<<<nc, 256, 0, stream>>>(out_map, selbin, ccount, cand);
    topk_kernel<<<B, 256, 0, stream>>>(cand, ccount, out_score);
}

// Round 10
// 127.848 us; speedup vs baseline: 1.6762x; 1.0013x over previous
//
#include <hip/hip_runtime.h>

constexpr int C = 768;
constexpr int NPATCH = 1024;   // (448/14)^2
constexpr int H = 448, W = 448;
constexpr int HW = H * W;      // 200704
constexpr int TOPK = 200;      // int(200704 * 0.001)
constexpr float EPS = 1e-12f;

constexpr int HBITS = 13;
constexpr int HBINS = 1 << HBITS;   // 8192
constexpr int HSHIFT = 18;          // bin = float_bits >> 18 (sign always 0)
constexpr int SLICES = 32;          // hist blocks per batch
constexpr int CSTRIDE = 64;         // ints between per-batch counters (256B)

typedef float f32x4 __attribute__((ext_vector_type(4)));

__device__ __forceinline__ float dotv(const f32x4 a, const f32x4 b) {
    return a.x * b.x + a.y * b.y + a.z * b.z + a.w * b.w;
}

// One wave per (b,n) row, nontemporal loads (bypass L2/L3 allocation path —
// measured: breaks the ~2.9 TB/s read plateau, anom ~70 -> ~20-25 us).
__global__ __launch_bounds__(256, 4) void anom_kernel(
    const float* __restrict__ m, const float* __restrict__ l,
    const float* __restrict__ pm, const float* __restrict__ pl,
    float* __restrict__ combined, int rows) {
    int wid = (int)((blockIdx.x * blockDim.x + threadIdx.x) >> 6);
    int lane = threadIdx.x & 63;
    if (wid >= rows) return;
    size_t base = (size_t)wid * C;
    const f32x4* A = (const f32x4*)(m + base);
    const f32x4* B = (const f32x4*)(pm + base);
    const f32x4* Cc = (const f32x4*)(l + base);
    const f32x4* D = (const f32x4*)(pl + base);

    f32x4 a0 = __builtin_nontemporal_load(A + lane);
    f32x4 a1 = __builtin_nontemporal_load(A + lane + 64);
    f32x4 a2 = __builtin_nontemporal_load(A + lane + 128);
    f32x4 b0 = __builtin_nontemporal_load(B + lane);
    f32x4 b1 = __builtin_nontemporal_load(B + lane + 64);
    f32x4 b2 = __builtin_nontemporal_load(B + lane + 128);
    f32x4 c0 = __builtin_nontemporal_load(Cc + lane);
    f32x4 c1 = __builtin_nontemporal_load(Cc + lane + 64);
    f32x4 c2 = __builtin_nontemporal_load(Cc + lane + 128);
    f32x4 d0 = __builtin_nontemporal_load(D + lane);
    f32x4 d1 = __builtin_nontemporal_load(D + lane + 64);
    f32x4 d2 = __builtin_nontemporal_load(D + lane + 128);

    float mm = dotv(a0, a0) + dotv(a1, a1) + dotv(a2, a2);
    float pp = dotv(b0, b0) + dotv(b1, b1) + dotv(b2, b2);
    float mp = dotv(a0, b0) + dotv(a1, b1) + dotv(a2, b2);
    float ll = dotv(c0, c0) + dotv(c1, c1) + dotv(c2, c2);
    float qq = dotv(d0, d0) + dotv(d1, d1) + dotv(d2, d2);
    float lq = dotv(c0, d0) + dotv(c1, d1) + dotv(c2, d2);

#pragma unroll
    for (int off = 32; off > 0; off >>= 1) {
        mm += __shfl_xor(mm, off);
        pp += __shfl_xor(pp, off);
        mp += __shfl_xor(mp, off);
        ll += __shfl_xor(ll, off);
        qq += __shfl_xor(qq, off);
        lq += __shfl_xor(lq, off);
    }
    if (lane == 0) {
        float rm = 1.0f / fmaxf(sqrtf(mm), EPS);
        float rp = 1.0f / fmaxf(sqrtf(pp), EPS);
        float rl = 1.0f / fmaxf(sqrtf(ll), EPS);
        float rq = 1.0f / fmaxf(sqrtf(qq), EPS);
        float d2m = fmaxf(mm * rm * rm - 2.f * mp * rm * rp + pp * rp * rp, 0.f);
        float d2l = fmaxf(ll * rl * rl - 2.f * lq * rl * rq + qq * rq * rq, 0.f);
        combined[wid] = sqrtf(d2m) * sqrtf(d2l);
    }
}

__device__ __forceinline__ float bilerp32(const float* __restrict__ s,
                                          int gy, int gx) {
    float sx = (gx + 0.5f) * (1.0f / 14.0f) - 0.5f;
    float sy = (gy + 0.5f) * (1.0f / 14.0f) - 0.5f;
    float fx0 = floorf(sx), fy0 = floorf(sy);
    float fx = sx - fx0, fy = sy - fy0;
    int x0 = (int)fx0, y0 = (int)fy0;
    int x0c = min(max(x0, 0), 31);
    int x1c = min(max(x0 + 1, 0), 31);
    int y0c = min(max(y0, 0), 31);
    int y1c = min(max(y0 + 1, 0), 31);
    float v00 = s[y0c * 32 + x0c], v01 = s[y0c * 32 + x1c];
    float v10 = s[y1c * 32 + x0c], v11 = s[y1c * 32 + x1c];
    return (1.f - fy) * ((1.f - fx) * v00 + fx * v01) +
           fy * ((1.f - fx) * v10 + fx * v11);
}

// Fused NP passes of (2P+1)^2 zero-padded box blur, 64x64 output tile,
// sliding-origin LDS scheme, TWO buffers (proven config); all LDS b128.
template <int P, int NP, bool UPS>
__global__ __launch_bounds__(512) void blur_fused_kernel(
    const float* __restrict__ src, float* __restrict__ dst) {
    constexpr int T = 64;
    constexpr int HALO = NP * P;
    constexpr int BS = T + 2 * HALO;   // 84 (P2) / 82 (P3)
    constexpr int BW = 84;             // row stride (words), mult of 4
    constexpr float inv = 1.0f / (2 * P + 1);
    __shared__ float buf[BS * BW];
    __shared__ float tmp[84 * BW];

    int tilex = blockIdx.x % 7;
    int tiley = (blockIdx.x / 7) % 7;
    int b = blockIdx.x / 49;
    int ox0 = tilex * T, oy0 = tiley * T;
    int tid = threadIdx.x;

    if (UPS) {
        const float* s = src + (size_t)b * NPATCH;
        for (int i = tid; i < NPATCH; i += 512) tmp[i] = s[i];
        __syncthreads();
        for (int i = tid; i < BS * BS; i += 512) {
            int r = i / BS, c = i % BS;
            int gy = oy0 + r - HALO, gx = ox0 + c - HALO;
            float v = 0.f;
            if (gy >= 0 && gy < H && gx >= 0 && gx < W) v = bilerp32(tmp, gy, gx);
            buf[r * BW + c] = v;
        }
    } else {
        const float* s = src + (size_t)b * HW;
        for (int i = tid; i < BS * BS; i += 512) {
            int r = i / BS, c = i % BS;
            int gy = oy0 + r - HALO, gx = ox0 + c - HALO;
            float v = 0.f;
            if (gy >= 0 && gy < H && gx >= 0 && gx < W) v = s[gy * W + gx];
            buf[r * BW + c] = v;
        }
    }
    __syncthreads();

#pragma unroll 1
    for (int pass = 0; pass < NP; ++pass) {
        int S = BS - 2 * pass * P;
        int wOut = S - 2 * P;
        int ncell = (wOut + 3) >> 2;
        int cellsH = S * ncell;
        for (int i = tid; i < cellsH; i += 512) {
            int r = i / ncell, cc = (i % ncell) * 4;
            const float* bp = &buf[r * BW + cc];
            float4 A = *(const float4*)bp;
            float4 Bv = *(const float4*)(bp + 4);
            float o0, o1, o2, o3;
            if (P == 2) {
                float t = A.x + A.y + A.z + A.w + Bv.x;
                o0 = t;
                t += Bv.y - A.x; o1 = t;
                t += Bv.z - A.y; o2 = t;
                t += Bv.w - A.z; o3 = t;
            } else {
                float4 Cv = *(const float4*)(bp + 8);
                float t = A.x + A.y + A.z + A.w + Bv.x + Bv.y + Bv.z;
                o0 = t;
                t += Bv.w - A.x; o1 = t;
                t += Cv.x - A.y; o2 = t;
                t += Cv.y - A.z; o3 = t;
            }
            *(float4*)&tmp[r * BW + cc] =
                make_float4(o0 * inv, o1 * inv, o2 * inv, o3 * inv);
        }
        __syncthreads();
        int org = (pass + 1) * P;
        int cellsV = wOut * ncell;
        for (int i = tid; i < cellsV; i += 512) {
            int r = i / ncell, cc = (i % ncell) * 4;
            float4 acc = *(const float4*)&tmp[r * BW + cc];
#pragma unroll
            for (int j = 1; j <= 2 * P; ++j) {
                float4 v = *(const float4*)&tmp[(r + j) * BW + cc];
                acc.x += v.x; acc.y += v.y; acc.z += v.z; acc.w += v.w;
            }
            int gy = oy0 - HALO + org + r;
            int gx = ox0 - HALO + org + cc;
            bool ry = (gy >= 0 && gy < H);
            float4 o;
            o.x = (ry && gx >= 0 && gx < W) ? acc.x * inv : 0.f;
            o.y = (ry && gx + 1 >= 0 && gx + 1 < W) ? acc.y * inv : 0.f;
            o.z = (ry && gx + 2 >= 0 && gx + 2 < W) ? acc.z * inv : 0.f;
            o.w = (ry && gx + 3 >= 0 && gx + 3 < W) ? acc.w * inv : 0.f;
            *(float4*)&buf[r * BW + cc] = o;
        }
        __syncthreads();
    }

    float* d = dst + (size_t)b * HW;
    for (int i = tid; i < T * (T / 4); i += 512) {
        int r = i / (T / 4), cc = (i % (T / 4)) * 4;
        *(float4*)&d[(size_t)(oy0 + r) * W + ox0 + cc] =
            *(const float4*)&buf[r * BW + cc];
    }
}

// ---------------- grid-parallel exact top-k ----------------

// 16B-per-thread zeroing (rocclr fillBuffer was 41 us for 520KB).
__global__ __launch_bounds__(256) void zero4_kernel(uint4* __restrict__ p,
                                                    int n4) {
    int i = blockIdx.x * blockDim.x + threadIdx.x;
    if (i < n4) p[i] = make_uint4(0u, 0u, 0u, 0u);
}

__global__ __launch_bounds__(256) void hist_kernel(
    const float* __restrict__ map, unsigned* __restrict__ hist) {
    __shared__ unsigned lh[HBINS];
    int b = blockIdx.x / SLICES, sl = blockIdx.x % SLICES;
    for (int i = threadIdx.x; i < HBINS; i += 256) lh[i] = 0;
    __syncthreads();
    const uint4* u4 = (const uint4*)(map + (size_t)b * HW);
    int per4 = HW / SLICES / 4;  // 1568
    int start = sl * per4;
    for (int i = start + threadIdx.x; i < start + per4; i += 256) {
        uint4 v = u4[i];
        atomicAdd(&lh[v.x >> HSHIFT], 1u);
        atomicAdd(&lh[v.y >> HSHIFT], 1u);
        atomicAdd(&lh[v.z >> HSHIFT], 1u);
        atomicAdd(&lh[v.w >> HSHIFT], 1u);
    }
    __syncthreads();
    unsigned* gh = hist + (size_t)b * HBINS;
    for (int i = threadIdx.x; i < HBINS; i += 256) {
        unsigned c = lh[i];
        if (c) atomicAdd(&gh[i], c);
    }
}

// Parallel suffix-scan select: largest bin with count(bins >= bin) >= TOPK.
__global__ __launch_bounds__(256) void select_kernel(
    const unsigned* __restrict__ hist, int* __restrict__ selbin) {
    int b = blockIdx.x;
    const unsigned* gh = hist + (size_t)b * HBINS;
    constexpr int CHUNK = HBINS / 256;  // 32
    __shared__ unsigned ss[257];
    __shared__ unsigned cs2[33];
    __shared__ int sh_base, sh_k;
    int tid = threadIdx.x;
    unsigned s = 0;
#pragma unroll
    for (int j = 0; j < CHUNK; ++j) s += gh[tid * CHUNK + j];
    ss[tid] = s;
    if (tid == 0) ss[256] = 0;
    __syncthreads();
#pragma unroll
    for (int st = 1; st < 256; st <<= 1) {
        unsigned add = (tid + st < 256) ? ss[tid + st] : 0u;
        __syncthreads();
        ss[tid] += add;
        __syncthreads();
    }
    if ((int)ss[tid] >= TOPK && (int)ss[tid + 1] < TOPK) {
        sh_base = tid * CHUNK;
        sh_k = TOPK - (int)ss[tid + 1];
    }
    __syncthreads();
    int base = sh_base, kk = sh_k;
    if (tid < 32) cs2[tid] = gh[base + tid];
    if (tid == 0) cs2[32] = 0;
    __syncthreads();
#pragma unroll
    for (int st = 1; st < 32; st <<= 1) {
        unsigned add = (tid < 32 && tid + st < 32) ? cs2[tid + st] : 0u;
        __syncthreads();
        if (tid < 32) cs2[tid] += add;
        __syncthreads();
    }
    if (tid < 32 && (int)cs2[tid] >= kk && (int)cs2[tid + 1] < kk)
        selbin[b * CSTRIDE] = base + tid;
}

__global__ __launch_bounds__(256) void compact_kernel(
    const float* __restrict__ map, const int* __restrict__ selbin,
    int* __restrict__ ccount, float* __restrict__ cand) {
    int tid = threadIdx.x;
    size_t base = (size_t)blockIdx.x * 1024;
    int b = (int)(base / HW);
    int sb = selbin[b * CSTRIDE];
    const uint4* u4 = (const uint4*)(((const unsigned*)map) + base);
    uint4 v = u4[tid];
    unsigned take0 = ((int)(v.x >> HSHIFT) >= sb);
    unsigned take1 = ((int)(v.y >> HSHIFT) >= sb);
    unsigned take2 = ((int)(v.z >> HSHIFT) >= sb);
    unsigned take3 = ((int)(v.w >> HSHIFT) >= sb);
    int c = (int)(take0 + take1 + take2 + take3);

    __shared__ int blkcnt, blkbase;
    if (tid == 0) blkcnt = 0;
    __syncthreads();
    int pos = 0;
    if (c) pos = atomicAdd(&blkcnt, c);
    __syncthreads();
    if (tid == 0 && blkcnt > 0)
        blkbase = atomicAdd(&ccount[b * CSTRIDE], blkcnt);
    __syncthreads();
    if (c) {
        float* o = cand + (size_t)b * HW + blkbase + pos;
        if (take0) *o++ = __uint_as_float(v.x);
        if (take1) *o++ = __uint_as_float(v.y);
        if (take2) *o++ = __uint_as_float(v.z);
        if (take3) *o = __uint_as_float(v.w);
    }
}

// Exact top-200 mean via radix select over candidates; per-digit bin scan
// is a parallel suffix-sum.
__global__ __launch_bounds__(256) void topk_kernel(
    const float* __restrict__ cand, const int* __restrict__ ccount,
    float* __restrict__ score) {
    int b = blockIdx.x;
    const float* s = cand + (size_t)b * HW;
    const unsigned* u = (const unsigned*)s;
    int M = ccount[b * CSTRIDE];
    __shared__ unsigned hist[256];
    __shared__ unsigned ss[257];
    __shared__ unsigned sh_prefix;
    __shared__ int sh_k;
    int tid = threadIdx.x;

    unsigned prefix = 0;
    int k = TOPK;
    for (int dgt = 3; dgt >= 0; --dgt) {
        hist[tid] = 0;
        __syncthreads();
        for (int i = tid; i < M; i += 256) {
            unsigned v = u[i];
            bool match = (dgt == 3) || ((v >> (8 * (dgt + 1))) == prefix);
            if (match) atomicAdd(&hist[(v >> (8 * dgt)) & 255u], 1u);
        }
        __syncthreads();
        ss[tid] = hist[tid];
        if (tid == 0) ss[256] = 0;
        __syncthreads();
#pragma unroll
        for (int st = 1; st < 256; st <<= 1) {
            unsigned add = (tid + st < 256) ? ss[tid + st] : 0u;
            __syncthreads();
            ss[tid] += add;
            __syncthreads();
        }
        if ((int)ss[tid] >= k && (int)ss[tid + 1] < k) {
            sh_prefix = (prefix << 8) | (unsigned)tid;
            sh_k = k - (int)ss[tid + 1];
        }
        __syncthreads();
        prefix = sh_prefix;
        k = sh_k;
        __syncthreads();
    }

    float thr = __uint_as_float(prefix);
    float sum = 0.f;
    int cnt = 0;
    for (int i = tid; i < M; i += 256) {
        float v = s[i];
        if (v > thr) { sum += v; cnt++; }
    }
#pragma unroll
    for (int off = 32; off > 0; off >>= 1) {
        sum += __shfl_xor(sum, off);
        cnt += __shfl_xor(cnt, off);
    }
    __shared__ float wsum[4];
    __shared__ int wcnt[4];
    int wv = tid >> 6;
    if ((tid & 63) == 0) { wsum[wv] = sum; wcnt[wv] = cnt; }
    __syncthreads();
    if (tid == 0) {
        float s2 = 0.f;
        int c2 = 0;
        for (int i = 0; i < 4; ++i) { s2 += wsum[i]; c2 += wcnt[i]; }
        score[b] = (s2 + (float)(TOPK - c2) * thr) * (1.0f / TOPK);
    }
}

extern "C" void kernel_launch(void* const* d_in, const int* in_sizes, int n_in,
                              void* d_out, int out_size, void* d_ws, size_t ws_size,
                              hipStream_t stream) {
    const float* mid = (const float*)d_in[0];
    const float* last = (const float*)d_in[1];
    const float* pmid = (const float*)d_in[2];
    const float* plast = (const float*)d_in[3];
    int B = in_sizes[0] / (NPATCH * C);  // 16

    float* out_map = (float*)d_out;                   // B*448*448
    float* out_score = out_map + (size_t)B * HW;      // B

    float* combined = (float*)d_ws;
    int* meta = (int*)((char*)d_ws + 64 * 1024);
    int* ccount = meta;                               // [b*CSTRIDE]
    int* selbin = meta + 16 * CSTRIDE;                // [b*CSTRIDE]
    float* bufA = (float*)((char*)d_ws + 72 * 1024);  // B*HW floats
    unsigned* hist = (unsigned*)bufA;                 // overlays bufA
    float* cand = bufA;                               // overlays bufA

    int rows = B * NPATCH;
    anom_kernel<<<(rows + 3) / 4, 256, 0, stream>>>(mid, last, pmid, plast,
                                                    combined, rows);
    int nblk = B * 49;
    blur_fused_kernel<2, 5, true><<<nblk, 512, 0, stream>>>(combined, bufA);
    blur_fused_kernel<3, 3, false><<<nblk, 512, 0, stream>>>(bufA, out_map);

    // zero meta (8KB) + hist (512KB): custom 16B/thread kernel
    int n4 = (8192 + B * HBINS * 4) / 16;  // 33280 uint4s
    zero4_kernel<<<(n4 + 255) / 256, 256, 0, stream>>>(
        (uint4*)((char*)d_ws + 64 * 1024), n4);
    hist_kernel<<<B * SLICES, 256, 0, stream>>>(out_map, hist);
    select_kernel<<<B, 256, 0, stream>>>(hist, selbin);
    int nc = (B * HW) / 1024;
    compact_kernel<<<nc, 256, 0, stream>>>(out_map, selbin, ccount, cand);
    topk_kernel<<<B, 256, 0, stream>>>(cand, ccount, out_score);
}

// Round 11
// 110.401 us; speedup vs baseline: 1.9411x; 1.1580x over previous
//
#include <hip/hip_runtime.h>

constexpr int C = 768;
constexpr int NPATCH = 1024;   // (448/14)^2
constexpr int H = 448, W = 448;
constexpr int HW = H * W;      // 200704
constexpr int TOPK = 200;      // int(200704 * 0.001)
constexpr float EPS = 1e-12f;

constexpr int HBITS = 13;
constexpr int HBINS = 1 << HBITS;   // 8192
constexpr int HSHIFT = 18;          // bin = float_bits >> 18 (sign always 0)
constexpr int SLICES = 32;          // hist blocks per batch
constexpr int CSTRIDE = 64;         // ints between per-batch counters (256B)

typedef float f32x4 __attribute__((ext_vector_type(4)));

__device__ __forceinline__ float dotv(const f32x4 a, const f32x4 b) {
    return a.x * b.x + a.y * b.y + a.z * b.z + a.w * b.w;
}

// One wave per (b,n) row, nontemporal loads (bypass L2/L3 allocation path —
// measured: breaks the ~2.9 TB/s read plateau, anom ~70 -> ~22 us).
__global__ __launch_bounds__(256, 4) void anom_kernel(
    const float* __restrict__ m, const float* __restrict__ l,
    const float* __restrict__ pm, const float* __restrict__ pl,
    float* __restrict__ combined, int rows) {
    int wid = (int)((blockIdx.x * blockDim.x + threadIdx.x) >> 6);
    int lane = threadIdx.x & 63;
    if (wid >= rows) return;
    size_t base = (size_t)wid * C;
    const f32x4* A = (const f32x4*)(m + base);
    const f32x4* B = (const f32x4*)(pm + base);
    const f32x4* Cc = (const f32x4*)(l + base);
    const f32x4* D = (const f32x4*)(pl + base);

    f32x4 a0 = __builtin_nontemporal_load(A + lane);
    f32x4 a1 = __builtin_nontemporal_load(A + lane + 64);
    f32x4 a2 = __builtin_nontemporal_load(A + lane + 128);
    f32x4 b0 = __builtin_nontemporal_load(B + lane);
    f32x4 b1 = __builtin_nontemporal_load(B + lane + 64);
    f32x4 b2 = __builtin_nontemporal_load(B + lane + 128);
    f32x4 c0 = __builtin_nontemporal_load(Cc + lane);
    f32x4 c1 = __builtin_nontemporal_load(Cc + lane + 64);
    f32x4 c2 = __builtin_nontemporal_load(Cc + lane + 128);
    f32x4 d0 = __builtin_nontemporal_load(D + lane);
    f32x4 d1 = __builtin_nontemporal_load(D + lane + 64);
    f32x4 d2 = __builtin_nontemporal_load(D + lane + 128);

    float mm = dotv(a0, a0) + dotv(a1, a1) + dotv(a2, a2);
    float pp = dotv(b0, b0) + dotv(b1, b1) + dotv(b2, b2);
    float mp = dotv(a0, b0) + dotv(a1, b1) + dotv(a2, b2);
    float ll = dotv(c0, c0) + dotv(c1, c1) + dotv(c2, c2);
    float qq = dotv(d0, d0) + dotv(d1, d1) + dotv(d2, d2);
    float lq = dotv(c0, d0) + dotv(c1, d1) + dotv(c2, d2);

#pragma unroll
    for (int off = 32; off > 0; off >>= 1) {
        mm += __shfl_xor(mm, off);
        pp += __shfl_xor(pp, off);
        mp += __shfl_xor(mp, off);
        ll += __shfl_xor(ll, off);
        qq += __shfl_xor(qq, off);
        lq += __shfl_xor(lq, off);
    }
    if (lane == 0) {
        float rm = 1.0f / fmaxf(sqrtf(mm), EPS);
        float rp = 1.0f / fmaxf(sqrtf(pp), EPS);
        float rl = 1.0f / fmaxf(sqrtf(ll), EPS);
        float rq = 1.0f / fmaxf(sqrtf(qq), EPS);
        float d2m = fmaxf(mm * rm * rm - 2.f * mp * rm * rp + pp * rp * rp, 0.f);
        float d2l = fmaxf(ll * rl * rl - 2.f * lq * rl * rq + qq * rq * rq, 0.f);
        combined[wid] = sqrtf(d2m) * sqrtf(d2l);
    }
}

// ---- upsample+blur as map = G * comb * G^T (exact linear factorization) ----
// G (448x32) = [8-pass 1D zero-pad box blur chain] applied to the clamped
// half-pixel bilinear basis. Valid because each 2D kxk zero-pad box conv =
// H∘V exactly, H-ops commute with V-ops under zero-extension, and bilinear
// upsample is a tensor product. Per-axis pass ORDER is preserved.

// One block, 512 threads = 32 columns x 16 chunks of 28 x-values.
// LDS layout [32][449]: stride 449 -> conflict-free scalar access.
__global__ __launch_bounds__(512) void gmat_kernel(float* __restrict__ G) {
    __shared__ float g[32][449];
    int tid = threadIdx.x;
    int i = tid & 31;       // grid column
    int chunk = tid >> 5;   // 0..15
    int x0 = chunk * 28;

    // init: clamped bilinear weight of grid col i at output x
#pragma unroll 1
    for (int k = 0; k < 28; ++k) {
        int x = x0 + k;
        float sx = (x + 0.5f) * (1.0f / 14.0f) - 0.5f;
        float f0 = floorf(sx);
        float fx = sx - f0;
        int q0 = (int)f0;
        int q0c = min(max(q0, 0), 31);
        int q1c = min(max(q0 + 1, 0), 31);
        float w = 0.f;
        if (q0c == i) w += 1.0f - fx;
        if (q1c == i) w += fx;
        g[i][x] = w;
    }
    __syncthreads();

#pragma unroll 1
    for (int pass = 0; pass < 8; ++pass) {
        float win[34];
#pragma unroll
        for (int j = 0; j < 34; ++j) {
            int xw = x0 - 3 + j;
            win[j] = (xw >= 0 && xw < 448) ? g[i][xw] : 0.f;
        }
        float out[28];
        if (pass < 5) {
            constexpr float inv5 = 1.0f / 5.0f;
#pragma unroll
            for (int k = 0; k < 28; ++k)
                out[k] = (win[k + 1] + win[k + 2] + win[k + 3] + win[k + 4] +
                          win[k + 5]) * inv5;
        } else {
            constexpr float inv7 = 1.0f / 7.0f;
#pragma unroll
            for (int k = 0; k < 28; ++k)
                out[k] = (win[k] + win[k + 1] + win[k + 2] + win[k + 3] +
                          win[k + 4] + win[k + 5] + win[k + 6]) * inv7;
        }
        __syncthreads();
#pragma unroll
        for (int k = 0; k < 28; ++k) g[i][x0 + k] = out[k];
        __syncthreads();
    }
#pragma unroll
    for (int k = 0; k < 28; ++k) G[(x0 + k) * 32 + i] = g[i][x0 + k];
}

// T[b][x][i] = sum_j G[x][j] * comb[b][i][j].  16 blocks (one per batch).
__global__ __launch_bounds__(448) void stageA_kernel(
    const float* __restrict__ comb, const float* __restrict__ G,
    float* __restrict__ T) {
    __shared__ float combT[32][32];  // [j][i]
    int b = blockIdx.x;
    int x = threadIdx.x;
    const float* cb = comb + (size_t)b * 1024;
    for (int idx = x; idx < 1024; idx += 448)
        combT[idx & 31][idx >> 5] = cb[idx];

    f32x4 grow[8];
#pragma unroll
    for (int k = 0; k < 8; ++k)
        grow[k] = *(const f32x4*)(G + x * 32 + k * 4);
    f32x4 acc[8];
#pragma unroll
    for (int k = 0; k < 8; ++k) acc[k] = (f32x4){0.f, 0.f, 0.f, 0.f};
    __syncthreads();
#pragma unroll
    for (int j = 0; j < 32; ++j) {
        float w = grow[j >> 2][j & 3];
#pragma unroll
        for (int k = 0; k < 8; ++k) {
            f32x4 c = *(const f32x4*)&combT[j][k * 4];
            acc[k] += c * w;
        }
    }
    float* t = T + ((size_t)b * 448 + x) * 32;
#pragma unroll
    for (int k = 0; k < 8; ++k) *(f32x4*)(t + k * 4) = acc[k];
}

// map[b][y][x] = sum_i G[y][i] * T[b][x][i].  256 blocks = 16 b x 16 bands.
// G in LDS stride-36 rows (16B-aligned, 8-way write conflict only on preload;
// reads are uniform-address broadcasts).
__global__ __launch_bounds__(448) void stageB_kernel(
    const float* __restrict__ T, const float* __restrict__ G,
    float* __restrict__ map) {
    __shared__ float gl[448 * 36];
    int b = blockIdx.x >> 4;
    int band = blockIdx.x & 15;
    int x = threadIdx.x;
#pragma unroll
    for (int k = 0; k < 8; ++k)
        *(f32x4*)&gl[x * 36 + k * 4] = *(const f32x4*)(G + x * 32 + k * 4);
    f32x4 t[8];
    const float* tp = T + ((size_t)b * 448 + x) * 32;
#pragma unroll
    for (int k = 0; k < 8; ++k) t[k] = *(const f32x4*)(tp + k * 4);
    __syncthreads();

    float* out = map + (size_t)b * HW + (size_t)band * 28 * W;
#pragma unroll 1
    for (int yy = 0; yy < 28; ++yy) {
        int y = band * 28 + yy;
        f32x4 a = {0.f, 0.f, 0.f, 0.f};
#pragma unroll
        for (int k = 0; k < 8; ++k) {
            f32x4 g4 = *(const f32x4*)&gl[y * 36 + k * 4];
            a += g4 * t[k];
        }
        out[yy * W + x] = a.x + a.y + a.z + a.w;
    }
}

// ---------------- grid-parallel exact top-k ----------------

__global__ __launch_bounds__(256) void zero4_kernel(uint4* __restrict__ p,
                                                    int n4) {
    int i = blockIdx.x * blockDim.x + threadIdx.x;
    if (i < n4) p[i] = make_uint4(0u, 0u, 0u, 0u);
}

__global__ __launch_bounds__(256) void hist_kernel(
    const float* __restrict__ map, unsigned* __restrict__ hist) {
    __shared__ unsigned lh[HBINS];
    int b = blockIdx.x / SLICES, sl = blockIdx.x % SLICES;
    for (int i = threadIdx.x; i < HBINS; i += 256) lh[i] = 0;
    __syncthreads();
    const uint4* u4 = (const uint4*)(map + (size_t)b * HW);
    int per4 = HW / SLICES / 4;  // 1568
    int start = sl * per4;
    for (int i = start + threadIdx.x; i < start + per4; i += 256) {
        uint4 v = u4[i];
        atomicAdd(&lh[v.x >> HSHIFT], 1u);
        atomicAdd(&lh[v.y >> HSHIFT], 1u);
        atomicAdd(&lh[v.z >> HSHIFT], 1u);
        atomicAdd(&lh[v.w >> HSHIFT], 1u);
    }
    __syncthreads();
    unsigned* gh = hist + (size_t)b * HBINS;
    for (int i = threadIdx.x; i < HBINS; i += 256) {
        unsigned c = lh[i];
        if (c) atomicAdd(&gh[i], c);
    }
}

// Parallel suffix-scan select: largest bin with count(bins >= bin) >= TOPK.
__global__ __launch_bounds__(256) void select_kernel(
    const unsigned* __restrict__ hist, int* __restrict__ selbin) {
    int b = blockIdx.x;
    const unsigned* gh = hist + (size_t)b * HBINS;
    constexpr int CHUNK = HBINS / 256;  // 32
    __shared__ unsigned ss[257];
    __shared__ unsigned cs2[33];
    __shared__ int sh_base, sh_k;
    int tid = threadIdx.x;
    unsigned s = 0;
#pragma unroll
    for (int j = 0; j < CHUNK; ++j) s += gh[tid * CHUNK + j];
    ss[tid] = s;
    if (tid == 0) ss[256] = 0;
    __syncthreads();
#pragma unroll
    for (int st = 1; st < 256; st <<= 1) {
        unsigned add = (tid + st < 256) ? ss[tid + st] : 0u;
        __syncthreads();
        ss[tid] += add;
        __syncthreads();
    }
    if ((int)ss[tid] >= TOPK && (int)ss[tid + 1] < TOPK) {
        sh_base = tid * CHUNK;
        sh_k = TOPK - (int)ss[tid + 1];
    }
    __syncthreads();
    int base = sh_base, kk = sh_k;
    if (tid < 32) cs2[tid] = gh[base + tid];
    if (tid == 0) cs2[32] = 0;
    __syncthreads();
#pragma unroll
    for (int st = 1; st < 32; st <<= 1) {
        unsigned add = (tid < 32 && tid + st < 32) ? cs2[tid + st] : 0u;
        __syncthreads();
        if (tid < 32) cs2[tid] += add;
        __syncthreads();
    }
    if (tid < 32 && (int)cs2[tid] >= kk && (int)cs2[tid + 1] < kk)
        selbin[b * CSTRIDE] = base + tid;
}

__global__ __launch_bounds__(256) void compact_kernel(
    const float* __restrict__ map, const int* __restrict__ selbin,
    int* __restrict__ ccount, float* __restrict__ cand) {
    int tid = threadIdx.x;
    size_t base = (size_t)blockIdx.x * 1024;
    int b = (int)(base / HW);
    int sb = selbin[b * CSTRIDE];
    const uint4* u4 = (const uint4*)(((const unsigned*)map) + base);
    uint4 v = u4[tid];
    unsigned take0 = ((int)(v.x >> HSHIFT) >= sb);
    unsigned take1 = ((int)(v.y >> HSHIFT) >= sb);
    unsigned take2 = ((int)(v.z >> HSHIFT) >= sb);
    unsigned take3 = ((int)(v.w >> HSHIFT) >= sb);
    int c = (int)(take0 + take1 + take2 + take3);

    __shared__ int blkcnt, blkbase;
    if (tid == 0) blkcnt = 0;
    __syncthreads();
    int pos = 0;
    if (c) pos = atomicAdd(&blkcnt, c);
    __syncthreads();
    if (tid == 0 && blkcnt > 0)
        blkbase = atomicAdd(&ccount[b * CSTRIDE], blkcnt);
    __syncthreads();
    if (c) {
        float* o = cand + (size_t)b * HW + blkbase + pos;
        if (take0) *o++ = __uint_as_float(v.x);
        if (take1) *o++ = __uint_as_float(v.y);
        if (take2) *o++ = __uint_as_float(v.z);
        if (take3) *o = __uint_as_float(v.w);
    }
}

// Exact top-200 mean via radix select over candidates (parallel suffix scans).
__global__ __launch_bounds__(256) void topk_kernel(
    const float* __restrict__ cand, const int* __restrict__ ccount,
    float* __restrict__ score) {
    int b = blockIdx.x;
    const float* s = cand + (size_t)b * HW;
    const unsigned* u = (const unsigned*)s;
    int M = ccount[b * CSTRIDE];
    __shared__ unsigned hist[256];
    __shared__ unsigned ss[257];
    __shared__ unsigned sh_prefix;
    __shared__ int sh_k;
    int tid = threadIdx.x;

    unsigned prefix = 0;
    int k = TOPK;
    for (int dgt = 3; dgt >= 0; --dgt) {
        hist[tid] = 0;
        __syncthreads();
        for (int i = tid; i < M; i += 256) {
            unsigned v = u[i];
            bool match = (dgt == 3) || ((v >> (8 * (dgt + 1))) == prefix);
            if (match) atomicAdd(&hist[(v >> (8 * dgt)) & 255u], 1u);
        }
        __syncthreads();
        ss[tid] = hist[tid];
        if (tid == 0) ss[256] = 0;
        __syncthreads();
#pragma unroll
        for (int st = 1; st < 256; st <<= 1) {
            unsigned add = (tid + st < 256) ? ss[tid + st] : 0u;
            __syncthreads();
            ss[tid] += add;
            __syncthreads();
        }
        if ((int)ss[tid] >= k && (int)ss[tid + 1] < k) {
            sh_prefix = (prefix << 8) | (unsigned)tid;
            sh_k = k - (int)ss[tid + 1];
        }
        __syncthreads();
        prefix = sh_prefix;
        k = sh_k;
        __syncthreads();
    }

    float thr = __uint_as_float(prefix);
    float sum = 0.f;
    int cnt = 0;
    for (int i = tid; i < M; i += 256) {
        float v = s[i];
        if (v > thr) { sum += v; cnt++; }
    }
#pragma unroll
    for (int off = 32; off > 0; off >>= 1) {
        sum += __shfl_xor(sum, off);
        cnt += __shfl_xor(cnt, off);
    }
    __shared__ float wsum[4];
    __shared__ int wcnt[4];
    int wv = tid >> 6;
    if ((tid & 63) == 0) { wsum[wv] = sum; wcnt[wv] = cnt; }
    __syncthreads();
    if (tid == 0) {
        float s2 = 0.f;
        int c2 = 0;
        for (int i = 0; i < 4; ++i) { s2 += wsum[i]; c2 += wcnt[i]; }
        score[b] = (s2 + (float)(TOPK - c2) * thr) * (1.0f / TOPK);
    }
}

extern "C" void kernel_launch(void* const* d_in, const int* in_sizes, int n_in,
                              void* d_out, int out_size, void* d_ws, size_t ws_size,
                              hipStream_t stream) {
    const float* mid = (const float*)d_in[0];
    const float* last = (const float*)d_in[1];
    const float* pmid = (const float*)d_in[2];
    const float* plast = (const float*)d_in[3];
    int B = in_sizes[0] / (NPATCH * C);  // 16

    float* out_map = (float*)d_out;                   // B*448*448
    float* out_score = out_map + (size_t)B * HW;      // B

    // ws layout
    float* combined = (float*)d_ws;                          // 0..64K
    int* meta = (int*)((char*)d_ws + 64 * 1024);             // 64K..72K
    int* ccount = meta;                                      // [b*CSTRIDE]
    int* selbin = meta + 16 * CSTRIDE;                       // [b*CSTRIDE]
    unsigned* hist = (unsigned*)((char*)d_ws + 72 * 1024);   // 72K..584K
    float* Gw = (float*)((char*)d_ws + 584 * 1024);          // 57,344B
    float* Tw = (float*)((char*)d_ws + 644 * 1024);          // 896KB
    float* cand = (float*)((char*)d_ws + 1540 * 1024);       // B*HW floats

    // zero meta (8KB) + hist (512KB): contiguous 520KB
    int n4 = (520 * 1024) / 16;
    zero4_kernel<<<(n4 + 255) / 256, 256, 0, stream>>>(
        (uint4*)((char*)d_ws + 64 * 1024), n4);

    gmat_kernel<<<1, 512, 0, stream>>>(Gw);

    int rows = B * NPATCH;
    anom_kernel<<<(rows + 3) / 4, 256, 0, stream>>>(mid, last, pmid, plast,
                                                    combined, rows);

    stageA_kernel<<<B, 448, 0, stream>>>(combined, Gw, Tw);
    stageB_kernel<<<B * 16, 448, 0, stream>>>(Tw, Gw, out_map);

    hist_kernel<<<B * SLICES, 256, 0, stream>>>(out_map, hist);
    select_kernel<<<B, 256, 0, stream>>>(hist, selbin);
    int nc = (B * HW) / 1024;
    compact_kernel<<<nc, 256, 0, stream>>>(out_map, selbin, ccount, cand);
    topk_kernel<<<B, 256, 0, stream>>>(cand, ccount, out_score);
}

// Round 12
// 100.600 us; speedup vs baseline: 2.1302x; 1.0974x over previous
//
#include <hip/hip_runtime.h>

constexpr int C = 768;
constexpr int NPATCH = 1024;   // (448/14)^2
constexpr int H = 448, W = 448;
constexpr int HW = H * W;      // 200704
constexpr int TOPK = 200;      // int(200704 * 0.001)
constexpr float EPS = 1e-12f;

constexpr int HBITS = 13;
constexpr int HBINS = 1 << HBITS;   // 8192
constexpr int HSHIFT = 18;          // bin = float_bits >> 18 (sign always 0)
constexpr int CSTRIDE = 64;         // ints between per-batch counters (256B)

typedef float f32x4 __attribute__((ext_vector_type(4)));

__device__ __forceinline__ float dotv(const f32x4 a, const f32x4 b) {
    return a.x * b.x + a.y * b.y + a.z * b.z + a.w * b.w;
}

// One wave per (b,n) row, nontemporal loads (bypass L2/L3 allocation path —
// measured: breaks the ~2.9 TB/s read plateau, anom ~70 -> ~22 us).
__global__ __launch_bounds__(256, 4) void anom_kernel(
    const float* __restrict__ m, const float* __restrict__ l,
    const float* __restrict__ pm, const float* __restrict__ pl,
    float* __restrict__ combined, int rows) {
    int wid = (int)((blockIdx.x * blockDim.x + threadIdx.x) >> 6);
    int lane = threadIdx.x & 63;
    if (wid >= rows) return;
    size_t base = (size_t)wid * C;
    const f32x4* A = (const f32x4*)(m + base);
    const f32x4* B = (const f32x4*)(pm + base);
    const f32x4* Cc = (const f32x4*)(l + base);
    const f32x4* D = (const f32x4*)(pl + base);

    f32x4 a0 = __builtin_nontemporal_load(A + lane);
    f32x4 a1 = __builtin_nontemporal_load(A + lane + 64);
    f32x4 a2 = __builtin_nontemporal_load(A + lane + 128);
    f32x4 b0 = __builtin_nontemporal_load(B + lane);
    f32x4 b1 = __builtin_nontemporal_load(B + lane + 64);
    f32x4 b2 = __builtin_nontemporal_load(B + lane + 128);
    f32x4 c0 = __builtin_nontemporal_load(Cc + lane);
    f32x4 c1 = __builtin_nontemporal_load(Cc + lane + 64);
    f32x4 c2 = __builtin_nontemporal_load(Cc + lane + 128);
    f32x4 d0 = __builtin_nontemporal_load(D + lane);
    f32x4 d1 = __builtin_nontemporal_load(D + lane + 64);
    f32x4 d2 = __builtin_nontemporal_load(D + lane + 128);

    float mm = dotv(a0, a0) + dotv(a1, a1) + dotv(a2, a2);
    float pp = dotv(b0, b0) + dotv(b1, b1) + dotv(b2, b2);
    float mp = dotv(a0, b0) + dotv(a1, b1) + dotv(a2, b2);
    float ll = dotv(c0, c0) + dotv(c1, c1) + dotv(c2, c2);
    float qq = dotv(d0, d0) + dotv(d1, d1) + dotv(d2, d2);
    float lq = dotv(c0, d0) + dotv(c1, d1) + dotv(c2, d2);

#pragma unroll
    for (int off = 32; off > 0; off >>= 1) {
        mm += __shfl_xor(mm, off);
        pp += __shfl_xor(pp, off);
        mp += __shfl_xor(mp, off);
        ll += __shfl_xor(ll, off);
        qq += __shfl_xor(qq, off);
        lq += __shfl_xor(lq, off);
    }
    if (lane == 0) {
        float rm = 1.0f / fmaxf(sqrtf(mm), EPS);
        float rp = 1.0f / fmaxf(sqrtf(pp), EPS);
        float rl = 1.0f / fmaxf(sqrtf(ll), EPS);
        float rq = 1.0f / fmaxf(sqrtf(qq), EPS);
        float d2m = fmaxf(mm * rm * rm - 2.f * mp * rm * rp + pp * rp * rp, 0.f);
        float d2l = fmaxf(ll * rl * rl - 2.f * lq * rl * rq + qq * rq * rq, 0.f);
        combined[wid] = sqrtf(d2m) * sqrtf(d2l);
    }
}

// ---- upsample+blur as map = G * comb * G^T (exact linear factorization) ----
// G (448x32) = [8-pass 1D zero-pad box blur chain] applied to the clamped
// half-pixel bilinear basis (H/V ops commute under zero-extension; per-axis
// pass order preserved).

// Fused init: block 0 builds G (512 thr = 32 cols x 16 chunks of 28 x);
// blocks 1..65 zero the 520KB meta+hist region (16B/thread).
__global__ __launch_bounds__(512) void init_kernel(float* __restrict__ G,
                                                   uint4* __restrict__ zp,
                                                   int n4) {
    if (blockIdx.x != 0) {
        int i = (blockIdx.x - 1) * 512 + threadIdx.x;
        if (i < n4) zp[i] = make_uint4(0u, 0u, 0u, 0u);
        return;
    }
    __shared__ float g[32][449];
    int tid = threadIdx.x;
    int i = tid & 31;       // grid column
    int chunk = tid >> 5;   // 0..15
    int x0 = chunk * 28;

#pragma unroll 1
    for (int k = 0; k < 28; ++k) {
        int x = x0 + k;
        float sx = (x + 0.5f) * (1.0f / 14.0f) - 0.5f;
        float f0 = floorf(sx);
        float fx = sx - f0;
        int q0 = (int)f0;
        int q0c = min(max(q0, 0), 31);
        int q1c = min(max(q0 + 1, 0), 31);
        float w = 0.f;
        if (q0c == i) w += 1.0f - fx;
        if (q1c == i) w += fx;
        g[i][x] = w;
    }
    __syncthreads();

#pragma unroll 1
    for (int pass = 0; pass < 8; ++pass) {
        float win[34];
#pragma unroll
        for (int j = 0; j < 34; ++j) {
            int xw = x0 - 3 + j;
            win[j] = (xw >= 0 && xw < 448) ? g[i][xw] : 0.f;
        }
        float out[28];
        if (pass < 5) {
            constexpr float inv5 = 1.0f / 5.0f;
#pragma unroll
            for (int k = 0; k < 28; ++k)
                out[k] = (win[k + 1] + win[k + 2] + win[k + 3] + win[k + 4] +
                          win[k + 5]) * inv5;
        } else {
            constexpr float inv7 = 1.0f / 7.0f;
#pragma unroll
            for (int k = 0; k < 28; ++k)
                out[k] = (win[k] + win[k + 1] + win[k + 2] + win[k + 3] +
                          win[k + 4] + win[k + 5] + win[k + 6]) * inv7;
        }
        __syncthreads();
#pragma unroll
        for (int k = 0; k < 28; ++k) g[i][x0 + k] = out[k];
        __syncthreads();
    }
#pragma unroll
    for (int k = 0; k < 28; ++k) G[(x0 + k) * 32 + i] = g[i][x0 + k];
}

// T[b][x][i] = sum_j G[x][j] * comb[b][i][j].  16 blocks (one per batch).
__global__ __launch_bounds__(448) void stageA_kernel(
    const float* __restrict__ comb, const float* __restrict__ G,
    float* __restrict__ T) {
    __shared__ float combT[32][32];  // [j][i]
    int b = blockIdx.x;
    int x = threadIdx.x;
    const float* cb = comb + (size_t)b * 1024;
    for (int idx = x; idx < 1024; idx += 448)
        combT[idx & 31][idx >> 5] = cb[idx];

    f32x4 grow[8];
#pragma unroll
    for (int k = 0; k < 8; ++k)
        grow[k] = *(const f32x4*)(G + x * 32 + k * 4);
    f32x4 acc[8];
#pragma unroll
    for (int k = 0; k < 8; ++k) acc[k] = (f32x4){0.f, 0.f, 0.f, 0.f};
    __syncthreads();
#pragma unroll
    for (int j = 0; j < 32; ++j) {
        float w = grow[j >> 2][j & 3];
#pragma unroll
        for (int k = 0; k < 8; ++k) {
            f32x4 c = *(const f32x4*)&combT[j][k * 4];
            acc[k] += c * w;
        }
    }
    float* t = T + ((size_t)b * 448 + x) * 32;
#pragma unroll
    for (int k = 0; k < 8; ++k) *(f32x4*)(t + k * 4) = acc[k];
}

// map[b][y][x] = sum_i G[y][i] * T[b][x][i], FUSED with per-batch histogram
// of the produced values (values live in registers here -> saves hist's
// 12.8MB map re-read + one launch).  256 blocks = 16 b x 16 bands.
__global__ __launch_bounds__(448) void stageB_kernel(
    const float* __restrict__ T, const float* __restrict__ G,
    float* __restrict__ map, unsigned* __restrict__ hist) {
    __shared__ float gband[28][32];   // G rows of this band (broadcast reads)
    __shared__ unsigned lh[HBINS];
    int b = blockIdx.x >> 4;
    int band = blockIdx.x & 15;
    int x = threadIdx.x;

    for (int i = x; i < HBINS; i += 448) lh[i] = 0;
    for (int i = x; i < 28 * 32; i += 448)
        gband[i >> 5][i & 31] = G[(band * 28 + (i >> 5)) * 32 + (i & 31)];
    f32x4 t[8];
    const float* tp = T + ((size_t)b * 448 + x) * 32;
#pragma unroll
    for (int k = 0; k < 8; ++k) t[k] = *(const f32x4*)(tp + k * 4);
    __syncthreads();

    float* out = map + (size_t)b * HW + (size_t)band * 28 * W;
#pragma unroll 1
    for (int yy = 0; yy < 28; ++yy) {
        f32x4 a = {0.f, 0.f, 0.f, 0.f};
#pragma unroll
        for (int k = 0; k < 8; ++k) {
            f32x4 g4 = *(const f32x4*)&gband[yy][k * 4];
            a += g4 * t[k];
        }
        float v = a.x + a.y + a.z + a.w;
        out[yy * W + x] = v;
        atomicAdd(&lh[__float_as_uint(v) >> HSHIFT], 1u);
    }
    __syncthreads();
    unsigned* gh = hist + (size_t)b * HBINS;
    for (int i = x; i < HBINS; i += 448) {
        unsigned c = lh[i];
        if (c) atomicAdd(&gh[i], c);
    }
}

// ---------------- grid-parallel exact top-k ----------------

// Parallel suffix-scan select: largest bin with count(bins >= bin) >= TOPK.
__global__ __launch_bounds__(256) void select_kernel(
    const unsigned* __restrict__ hist, int* __restrict__ selbin) {
    int b = blockIdx.x;
    const unsigned* gh = hist + (size_t)b * HBINS;
    constexpr int CHUNK = HBINS / 256;  // 32
    __shared__ unsigned ss[257];
    __shared__ unsigned cs2[33];
    __shared__ int sh_base, sh_k;
    int tid = threadIdx.x;
    unsigned s = 0;
#pragma unroll
    for (int j = 0; j < CHUNK; ++j) s += gh[tid * CHUNK + j];
    ss[tid] = s;
    if (tid == 0) ss[256] = 0;
    __syncthreads();
#pragma unroll
    for (int st = 1; st < 256; st <<= 1) {
        unsigned add = (tid + st < 256) ? ss[tid + st] : 0u;
        __syncthreads();
        ss[tid] += add;
        __syncthreads();
    }
    if ((int)ss[tid] >= TOPK && (int)ss[tid + 1] < TOPK) {
        sh_base = tid * CHUNK;
        sh_k = TOPK - (int)ss[tid + 1];
    }
    __syncthreads();
    int base = sh_base, kk = sh_k;
    if (tid < 32) cs2[tid] = gh[base + tid];
    if (tid == 0) cs2[32] = 0;
    __syncthreads();
#pragma unroll
    for (int st = 1; st < 32; st <<= 1) {
        unsigned add = (tid < 32 && tid + st < 32) ? cs2[tid + st] : 0u;
        __syncthreads();
        if (tid < 32) cs2[tid] += add;
        __syncthreads();
    }
    if (tid < 32 && (int)cs2[tid] >= kk && (int)cs2[tid + 1] < kk)
        selbin[b * CSTRIDE] = base + tid;
}

__global__ __launch_bounds__(256) void compact_kernel(
    const float* __restrict__ map, const int* __restrict__ selbin,
    int* __restrict__ ccount, float* __restrict__ cand) {
    int tid = threadIdx.x;
    size_t base = (size_t)blockIdx.x * 1024;
    int b = (int)(base / HW);
    int sb = selbin[b * CSTRIDE];
    const uint4* u4 = (const uint4*)(((const unsigned*)map) + base);
    uint4 v = u4[tid];
    unsigned take0 = ((int)(v.x >> HSHIFT) >= sb);
    unsigned take1 = ((int)(v.y >> HSHIFT) >= sb);
    unsigned take2 = ((int)(v.z >> HSHIFT) >= sb);
    unsigned take3 = ((int)(v.w >> HSHIFT) >= sb);
    int c = (int)(take0 + take1 + take2 + take3);

    __shared__ int blkcnt, blkbase;
    if (tid == 0) blkcnt = 0;
    __syncthreads();
    int pos = 0;
    if (c) pos = atomicAdd(&blkcnt, c);
    __syncthreads();
    if (tid == 0 && blkcnt > 0)
        blkbase = atomicAdd(&ccount[b * CSTRIDE], blkcnt);
    __syncthreads();
    if (c) {
        float* o = cand + (size_t)b * HW + blkbase + pos;
        if (take0) *o++ = __uint_as_float(v.x);
        if (take1) *o++ = __uint_as_float(v.y);
        if (take2) *o++ = __uint_as_float(v.z);
        if (take3) *o = __uint_as_float(v.w);
    }
}

// Exact top-200 mean via radix select over candidates (parallel suffix scans).
__global__ __launch_bounds__(256) void topk_kernel(
    const float* __restrict__ cand, const int* __restrict__ ccount,
    float* __restrict__ score) {
    int b = blockIdx.x;
    const float* s = cand + (size_t)b * HW;
    const unsigned* u = (const unsigned*)s;
    int M = ccount[b * CSTRIDE];
    __shared__ unsigned hist[256];
    __shared__ unsigned ss[257];
    __shared__ unsigned sh_prefix;
    __shared__ int sh_k;
    int tid = threadIdx.x;

    unsigned prefix = 0;
    int k = TOPK;
    for (int dgt = 3; dgt >= 0; --dgt) {
        hist[tid] = 0;
        __syncthreads();
        for (int i = tid; i < M; i += 256) {
            unsigned v = u[i];
            bool match = (dgt == 3) || ((v >> (8 * (dgt + 1))) == prefix);
            if (match) atomicAdd(&hist[(v >> (8 * dgt)) & 255u], 1u);
        }
        __syncthreads();
        ss[tid] = hist[tid];
        if (tid == 0) ss[256] = 0;
        __syncthreads();
#pragma unroll
        for (int st = 1; st < 256; st <<= 1) {
            unsigned add = (tid + st < 256) ? ss[tid + st] : 0u;
            __syncthreads();
            ss[tid] += add;
            __syncthreads();
        }
        if ((int)ss[tid] >= k && (int)ss[tid + 1] < k) {
            sh_prefix = (prefix << 8) | (unsigned)tid;
            sh_k = k - (int)ss[tid + 1];
        }
        __syncthreads();
        prefix = sh_prefix;
        k = sh_k;
        __syncthreads();
    }

    float thr = __uint_as_float(prefix);
    float sum = 0.f;
    int cnt = 0;
    for (int i = tid; i < M; i += 256) {
        float v = s[i];
        if (v > thr) { sum += v; cnt++; }
    }
#pragma unroll
    for (int off = 32; off > 0; off >>= 1) {
        sum += __shfl_xor(sum, off);
        cnt += __shfl_xor(cnt, off);
    }
    __shared__ float wsum[4];
    __shared__ int wcnt[4];
    int wv = tid >> 6;
    if ((tid & 63) == 0) { wsum[wv] = sum; wcnt[wv] = cnt; }
    __syncthreads();
    if (tid == 0) {
        float s2 = 0.f;
        int c2 = 0;
        for (int i = 0; i < 4; ++i) { s2 += wsum[i]; c2 += wcnt[i]; }
        score[b] = (s2 + (float)(TOPK - c2) * thr) * (1.0f / TOPK);
    }
}

extern "C" void kernel_launch(void* const* d_in, const int* in_sizes, int n_in,
                              void* d_out, int out_size, void* d_ws, size_t ws_size,
                              hipStream_t stream) {
    const float* mid = (const float*)d_in[0];
    const float* last = (const float*)d_in[1];
    const float* pmid = (const float*)d_in[2];
    const float* plast = (const float*)d_in[3];
    int B = in_sizes[0] / (NPATCH * C);  // 16

    float* out_map = (float*)d_out;                   // B*448*448
    float* out_score = out_map + (size_t)B * HW;      // B

    // ws layout
    float* combined = (float*)d_ws;                          // 0..64K
    int* meta = (int*)((char*)d_ws + 64 * 1024);             // 64K..72K
    int* ccount = meta;                                      // [b*CSTRIDE]
    int* selbin = meta + 16 * CSTRIDE;                       // [b*CSTRIDE]
    unsigned* hist = (unsigned*)((char*)d_ws + 72 * 1024);   // 72K..584K
    float* Gw = (float*)((char*)d_ws + 584 * 1024);          // 57,344B
    float* Tw = (float*)((char*)d_ws + 644 * 1024);          // 896KB
    float* cand = (float*)((char*)d_ws + 1540 * 1024);       // B*HW floats

    // block 0: build G; blocks 1..65: zero meta+hist (520KB)
    int n4 = (520 * 1024) / 16;
    init_kernel<<<1 + (n4 + 511) / 512, 512, 0, stream>>>(
        Gw, (uint4*)((char*)d_ws + 64 * 1024), n4);

    int rows = B * NPATCH;
    anom_kernel<<<(rows + 3) / 4, 256, 0, stream>>>(mid, last, pmid, plast,
                                                    combined, rows);

    stageA_kernel<<<B, 448, 0, stream>>>(combined, Gw, Tw);
    stageB_kernel<<<B * 16, 448, 0, stream>>>(Tw, Gw, out_map, hist);

    select_kernel<<<B, 256, 0, stream>>>(hist, selbin);
    int nc = (B * HW) / 1024;
    compact_kernel<<<nc, 256, 0, stream>>>(out_map, selbin, ccount, cand);
    topk_kernel<<<B, 256, 0, stream>>>(cand, ccount, out_score);
}